// Round 4
// baseline (6642.486 us; speedup 1.0000x reference)
//
#include <hip/hip_runtime.h>

typedef unsigned short u16;
typedef unsigned int u32;
typedef unsigned long long u64;
typedef __bf16 bf16x8 __attribute__((ext_vector_type(8)));
typedef float f32x4 __attribute__((ext_vector_type(4)));

__device__ __forceinline__ float bf2f(u16 u) { return __uint_as_float(((u32)u) << 16); }
__device__ __forceinline__ u16 f2bf(float f) {
    u32 u = __float_as_uint(f);
    u32 r = (u + 0x7FFFu + ((u >> 16) & 1u)) >> 16;
    return (u16)r;
}
__device__ __forceinline__ float sigm(float x) { return 1.0f / (1.0f + __expf(-x)); }
__device__ __forceinline__ float elu1(float x) { return x > 0.0f ? x + 1.0f : __expf(x); }

// agent-scope (LLC) atomics — HW-validated cross-XCD path (R5/R7)
__device__ __forceinline__ int ag_load(const int* p) {
    return __hip_atomic_load(p, __ATOMIC_RELAXED, __HIP_MEMORY_SCOPE_AGENT);
}
__device__ __forceinline__ void ag_store(int* p, int v) {
    __hip_atomic_store(p, v, __ATOMIC_RELAXED, __HIP_MEMORY_SCOPE_AGENT);
}
__device__ __forceinline__ void llc_store2(u16* p, u16 a, u16 b) {
    u32 v = (u32)a | ((u32)b << 16);
    __hip_atomic_store((u32*)p, v, __ATOMIC_RELAXED, __HIP_MEMORY_SCOPE_AGENT);
}
__device__ __forceinline__ void llc_store_u16(u16* p, u16 v) {
    __hip_atomic_store(p, v, __ATOMIC_RELAXED, __HIP_MEMORY_SCOPE_AGENT);
}

// ---------------------------------------------------------------------------
struct Cvt8 { const float* s[8]; u16* d[8]; int off4[9]; };

__global__ __launch_bounds__(256) void k_f2b8(Cvt8 c)
{
    int i = blockIdx.x * 256 + threadIdx.x;
    if (i >= c.off4[8]) return;
    int k = 0;
#pragma unroll
    for (int q = 1; q < 8; q++) if (i >= c.off4[q]) k = q;
    int j = i - c.off4[k];
    float4 v = ((const float4*)c.s[k])[j];
    ushort4 o;
    o.x = f2bf(v.x); o.y = f2bf(v.y); o.z = f2bf(v.z); o.w = f2bf(v.w);
    ((ushort4*)c.d[k])[j] = o;
}

// ---------------------------------------------------------------------------
__global__ __launch_bounds__(256) void k_embed(const int* __restrict__ tok,
                                               const float* __restrict__ W,
                                               u16* __restrict__ out)
{
    int c = blockIdx.x * 256 + threadIdx.x;
    int row = c >> 5, cc = (c & 31) * 8;
    int t = tok[row];
    const float* src = W + (size_t)t * 256 + cc;
    u16 tmp[8];
#pragma unroll
    for (int k = 0; k < 8; k++) tmp[k] = f2bf(src[k]);
    *(uint4*)(out + (size_t)row * 256 + cc) = *(uint4*)tmp;
}

// ---------------------------------------------------------------------------
// GEMM:  C[M,N] = A[M,K](bf16, lda) * B[N,K]^T(bf16) + bias. 128x128 tile.
// ---------------------------------------------------------------------------
__global__ __launch_bounds__(256) void k_gemm_bt(
    const u16* __restrict__ A, int lda,
    const u16* __restrict__ B,
    u16* __restrict__ Cb, float* __restrict__ Cf, int ldc,
    const float* __restrict__ bias1, const float* __restrict__ bias2,
    int N, int K)
{
    __shared__ u16 As[128][40];
    __shared__ u16 Bs[128][40];
    const int tid = threadIdx.x;
    const int m0 = blockIdx.x * 128, n0 = blockIdx.y * 128;
    const int wave = tid >> 6, lane = tid & 63;
    const int wm = wave & 1, wn = wave >> 1;
    const int quad = lane >> 4, l16 = lane & 15;
    f32x4 acc[4][4] = {};
    for (int k0 = 0; k0 < K; k0 += 32) {
        __syncthreads();
#pragma unroll
        for (int i = 0; i < 2; i++) {
            int c = tid + i * 256, row = c >> 2, cc = (c & 3) * 8;
            *(uint4*)(&As[row][cc]) = *(const uint4*)(A + (size_t)(m0 + row) * lda + k0 + cc);
            uint4 d = {0, 0, 0, 0};
            if (n0 + row < N) d = *(const uint4*)(B + (size_t)(n0 + row) * K + k0 + cc);
            *(uint4*)(&Bs[row][cc]) = d;
        }
        __syncthreads();
        bf16x8 af[4], bfm[4];
#pragma unroll
        for (int x = 0; x < 4; x++) {
            af[x]  = *(const bf16x8*)(&As[wm * 64 + x * 16 + l16][quad * 8]);
            bfm[x] = *(const bf16x8*)(&Bs[wn * 64 + x * 16 + l16][quad * 8]);
        }
#pragma unroll
        for (int mi = 0; mi < 4; mi++)
#pragma unroll
            for (int ni = 0; ni < 4; ni++)
                acc[mi][ni] = __builtin_amdgcn_mfma_f32_16x16x32_bf16(af[mi], bfm[ni], acc[mi][ni], 0, 0, 0);
    }
#pragma unroll
    for (int ni = 0; ni < 4; ni++) {
        int col = n0 + wn * 64 + ni * 16 + l16;
        if (col < N) {
            float bv = 0.f;
            if (bias1) bv += bias1[col];
            if (bias2) bv += bias2[col];
#pragma unroll
            for (int mi = 0; mi < 4; mi++) {
                int r0 = m0 + wm * 64 + mi * 16 + quad * 4;
#pragma unroll
                for (int r = 0; r < 4; r++) {
                    float v = acc[mi][ni][r] + bv;
                    if (Cb) Cb[(size_t)(r0 + r) * ldc + col] = f2bf(v);
                    else    Cf[(size_t)(r0 + r) * ldc + col] = v;
                }
            }
        }
    }
}

// ---------------------------------------------------------------------------
// Slot attention (standalone, R5-proven). 8 positions/block.
// ---------------------------------------------------------------------------
template <int NSLOT>
__global__ __launch_bounds__(256) void k_slot(
    const u16* __restrict__ dec, const u16* __restrict__ initp,
    const float* __restrict__ Wq, const float* __restrict__ bq,
    const float* __restrict__ Wk, const float* __restrict__ bk,
    const float* __restrict__ Wv, const float* __restrict__ bv,
    const float* __restrict__ lng, const float* __restrict__ lnb,
    const float* __restrict__ Wm1, const float* __restrict__ bm1,
    const float* __restrict__ Wm2, const float* __restrict__ bm2,
    const float* __restrict__ Wsp, const float* __restrict__ bsp,
    float* __restrict__ o1, float* __restrict__ o2, float* __restrict__ o3)
{
    __shared__ float WqT[32][33], WkT[64][33], WvT[64][33], Wm1T[32][65], Wm2T[64][33], WspT[64][33];
    __shared__ float bq_s[32], bk_s[32], bv_s[32], bm1_s[64], bm2_s[32], bsp_s[32], g_s[32], be_s[32];
    __shared__ u16 xbuf[8][192];
    __shared__ float slots[8][3][32], initl[8][3][32], kk[8][3][32], vv[8][3][32], qq[8][3][32];
    __shared__ float att[8][3][4];
    __shared__ float ubuf[8][32];
    __shared__ float hid[8][64];
    const int tid = threadIdx.x;
    for (int i = tid; i < 1024; i += 256) { int o = i >> 5, c = i & 31; WqT[c][o] = Wq[o * 32 + c]; }
    for (int i = tid; i < 2048; i += 256) {
        int o6 = i >> 6, c6 = i & 63;
        WkT[c6][o6]  = Wk[o6 * 64 + c6];
        WvT[c6][o6]  = Wv[o6 * 64 + c6];
        Wm2T[c6][o6] = Wm2[o6 * 64 + c6];
        WspT[c6][o6] = Wsp[o6 * 64 + c6];
        int o5 = i >> 5, c5 = i & 31;
        Wm1T[c5][o5] = Wm1[o5 * 32 + c5];
    }
    if (tid < 32) {
        bq_s[tid] = bq[tid]; bk_s[tid] = bk[tid]; bv_s[tid] = bv[tid];
        bm2_s[tid] = bm2[tid]; bsp_s[tid] = bsp[tid];
        g_s[tid] = lng[tid]; be_s[tid] = lnb[tid];
    }
    if (tid < 64) bm1_s[tid] = bm1[tid];
    const int p = tid >> 5, l = tid & 31;
    const size_t row = (size_t)blockIdx.x * 8 + p;
    for (int i = l; i < 192; i += 32) xbuf[p][i] = dec[row * 192 + i];
    __syncthreads();
#pragma unroll
    for (int i = 0; i < 3; i++) {
        float aK = bk_s[l], aV = bv_s[l];
        for (int c = 0; c < 64; c++) {
            float x = bf2f(xbuf[p][i * 64 + c]);
            aK += x * WkT[c][l];
            aV += x * WvT[c][l];
        }
        kk[p][i][l] = elu1(aK);
        vv[p][i][l] = aV;
    }
#pragma unroll
    for (int j = 0; j < NSLOT; j++) {
        float iv = bf2f(initp[row * (NSLOT * 32) + j * 32 + l]);
        initl[p][j][l] = iv;
        slots[p][j][l] = iv;
    }
    __syncthreads();
    const float rs = 0.17677669529663687f;
    for (int it = 0; it < 3; it++) {
#pragma unroll
        for (int j = 0; j < NSLOT; j++) {
            float a = bq_s[l];
            for (int c = 0; c < 32; c++) a += slots[p][j][c] * WqT[c][l];
            qq[p][j][l] = elu1((a + initl[p][j][l]) * rs);
        }
        __syncthreads();
        if (l < 3 * NSLOT) {
            int i = l / NSLOT, j = l % NSLOT;
            float s = 0.f;
            for (int c = 0; c < 32; c++) s += kk[p][i][c] * qq[p][j][c];
            att[p][i][j] = s;
        }
        __syncthreads();
        if (l < 3) {
            float mx = -1e30f;
            for (int j = 0; j < NSLOT; j++) mx = fmaxf(mx, att[p][l][j]);
            float sm = 0.f, ex[NSLOT];
            for (int j = 0; j < NSLOT; j++) { ex[j] = __expf(att[p][l][j] - mx); sm += ex[j]; }
            for (int j = 0; j < NSLOT; j++) att[p][l][j] = ex[j] / sm + 1e-8f;
        }
        __syncthreads();
        if (l < NSLOT) {
            float s = att[p][0][l] + att[p][1][l] + att[p][2][l];
            float inv = 1.0f / s;
            for (int i = 0; i < 3; i++) att[p][i][l] *= inv;
        }
        __syncthreads();
#pragma unroll
        for (int j = 0; j < NSLOT; j++) {
            float u = att[p][0][j] * vv[p][0][l] + att[p][1][j] * vv[p][1][l] + att[p][2][j] * vv[p][2][l];
            float mean = u;
            for (int mk = 1; mk < 32; mk <<= 1) mean += __shfl_xor(mean, mk, 32);
            mean *= (1.0f / 32.0f);
            float d = u - mean;
            float var = d * d;
            for (int mk = 1; mk < 32; mk <<= 1) var += __shfl_xor(var, mk, 32);
            var *= (1.0f / 32.0f);
            float y = d * rsqrtf(var + 1e-5f) * g_s[l] + be_s[l];
            ubuf[p][l] = y;
            __syncthreads();
#pragma unroll
            for (int oo = 0; oo < 2; oo++) {
                int o = l + oo * 32;
                float a = bm1_s[o];
                for (int c = 0; c < 32; c++) a += ubuf[p][c] * Wm1T[c][o];
                hid[p][o] = fmaxf(a, 0.f);
            }
            __syncthreads();
            float a2 = bm2_s[l];
            for (int c = 0; c < 64; c++) a2 += hid[p][c] * Wm2T[c][l];
            slots[p][j][l] += a2 * (1.0f / 32.0f);
            __syncthreads();
        }
    }
    float pj[NSLOT];
#pragma unroll
    for (int j = 0; j < NSLOT; j++) {
        float a = bsp_s[l];
        for (int c = 0; c < 32; c++) a += initl[p][j][c] * WspT[c][l];
        for (int c = 0; c < 32; c++) a += slots[p][j][c] * WspT[32 + c][l];
        pj[j] = a;
    }
    const float e = 1e-6f, me = (float)(1.0 - 2e-6);
    if (NSLOT == 3) {
        o1[row * 32 + l] = tanhf(me * pj[0] + e * pj[1] + e * pj[2]);
        o2[row * 32 + l] = tanhf(e * pj[0] + me * pj[1] + e * pj[2]);
        o3[row * 32 + l] = tanhf(e * pj[0] + e * pj[1] + me * pj[2]);
    } else {
        o1[row * 32 + l] = tanhf(me * pj[0] + e * pj[1]);
        o2[row * 32 + l] = tanhf(e * pj[0] + me * pj[1]);
    }
}

// ---------------------------------------------------------------------------
// Mega kernel: 192 blocks. Wave-autonomous LSTM; block-major h layout (R10).
// R11 sync: PACKED flag arrays — flag[g*64+j] at 4 B stride (4 lines/group)
//   - publishes stay per-block distinct-WORD plain agent stores (parallel;
//     LLC merges words — R8's serialized shared-counter mistake NOT repeated)
//   - polls become ONE coalesced 4-line gather instead of 64-line gather:
//     16x fewer LLC transactions per poll round (~320 waves spin constantly)
// Layer-1: single drain (h1seq + acat stores, one waitcnt, one publish f1
// covering both); combined f0/f1 poll (one detect phase per step).
// 4-way MFMA accumulators (even/odd kc) halve dependent-chain stalls.
//   flags: f0 = flags[0..255], f1 = flags[256..511]  (int index g*64+j)
// ---------------------------------------------------------------------------
__global__ __launch_bounds__(256) void k_mega(
    const u16* __restrict__ emb,
    const u16* __restrict__ Wx0, const u16* __restrict__ Wh0,
    const u16* __restrict__ Wx1, const u16* __restrict__ Wh1,
    const float* __restrict__ bi0, const float* __restrict__ bh0,
    const float* __restrict__ bi1, const float* __restrict__ bh1,
    u16* __restrict__ h0seq,        // [512][64][64][8] block-major
    u16* __restrict__ h1seq,        // [512][64][64][8] block-major
    u16* __restrict__ acat,         // [32768][544]; cols 0..511 h1, 512.. scan out
    int* __restrict__ flags,
    const float* __restrict__ r1, const float* __restrict__ r2,
    const float* __restrict__ fi, const float* __restrict__ uu1,
    const float* __restrict__ uu2,
    const float* __restrict__ Wg, const float* __restrict__ bg)
{
    const int tid = threadIdx.x;
    const int blk = blockIdx.x;
    int* f0 = flags;
    int* f1 = flags + 256;

    if (blk < 128) {
        // =================== wave-autonomous LSTM ======================
        __shared__ u16 Wx[32][528];
        __shared__ u16 Wh[32][528];
        __shared__ float zs[4][16][33];
        const int layer = blk >> 6;
        const int me = blk & 63;
        const int jbase = me * 8;
        const int Kx = layer ? 512 : 256;
        const u16* Wxp = layer ? Wx1 : Wx0;
        const u16* Whp = layer ? Wh1 : Wh0;
        const float* bi = layer ? bi1 : bi0;
        const float* bh = layer ? bh1 : bh0;
#pragma unroll
        for (int i = 0; i < 8; i++) {
            int c = tid + i * 256;
            int row = c >> 6, cc = (c & 63) * 8;
            int grow = (row >> 3) * 512 + jbase + (row & 7);
            *(uint4*)(&Wh[row][cc]) = *(const uint4*)(Whp + (size_t)grow * 512 + cc);
        }
        {
            int cpr = Kx >> 3;
            int iters = (32 * cpr) >> 8;
            for (int i = 0; i < iters; i++) {
                int c = tid + i * 256;
                int row = c / cpr, cc = (c % cpr) * 8;
                int grow = (row >> 3) * 512 + jbase + (row & 7);
                *(uint4*)(&Wx[row][cc]) = *(const uint4*)(Wxp + (size_t)grow * Kx + cc);
            }
        }
        const int wave = tid >> 6, lane = tid & 63;
        const int quad = lane >> 4, l16 = lane & 15;
        const int m = wave * 16 + l16;       // global batch row for MFMA A-load
        const int bl = lane >> 2;            // local batch (0..15)
        const int b = wave * 16 + bl;        // global batch for elementwise
        const int jj = (lane & 3) * 2;       // local col pair
        const int hoff = quad * 512 + m * 8; // block-major read offset (elements)
        float bia0[4], bia1[4];
#pragma unroll
        for (int g = 0; g < 4; g++) {
            bia0[g] = bi[g * 512 + jbase + jj]     + bh[g * 512 + jbase + jj];
            bia1[g] = bi[g * 512 + jbase + jj + 1] + bh[g * 512 + jbase + jj + 1];
        }
        int* pollF0 = f0 + wave * 64 + lane;   // packed: lane l polls word l of group `wave`
        int* pollF1 = f1 + wave * 64 + lane;
        int* pubF   = (layer ? f1 : f0) + wave * 64 + me;
        float c0 = 0.f, c1 = 0.f;
        __syncthreads();   // Wx/Wh staged; last barrier before the loop
        for (int t = 0; t < 512; t++) {
            f32x4 acc0 = {}, acc1 = {}, acc2 = {}, acc3 = {};
            if (!layer) {
                // x-part (emb, independent of flags)
                const u16* xrow = emb + ((size_t)t * 64 + m) * 256;
#pragma unroll
                for (int kc = 0; kc < 8; kc += 2) {
                    bf16x8 a0 = *(const bf16x8*)(xrow + kc * 32 + quad * 8);
                    bf16x8 a1 = *(const bf16x8*)(xrow + (kc + 1) * 32 + quad * 8);
                    acc0 = __builtin_amdgcn_mfma_f32_16x16x32_bf16(a0, *(const bf16x8*)(&Wx[l16][kc * 32 + quad * 8]), acc0, 0, 0, 0);
                    acc1 = __builtin_amdgcn_mfma_f32_16x16x32_bf16(a0, *(const bf16x8*)(&Wx[16 + l16][kc * 32 + quad * 8]), acc1, 0, 0, 0);
                    acc2 = __builtin_amdgcn_mfma_f32_16x16x32_bf16(a1, *(const bf16x8*)(&Wx[l16][(kc + 1) * 32 + quad * 8]), acc2, 0, 0, 0);
                    acc3 = __builtin_amdgcn_mfma_f32_16x16x32_bf16(a1, *(const bf16x8*)(&Wx[16 + l16][(kc + 1) * 32 + quad * 8]), acc3, 0, 0, 0);
                }
                if (t > 0) {   // wait for group-w h0[t-1]
                    int it = 0;
                    for (;;) {
                        int a = ag_load(pollF0);
                        if (__all(a >= t)) break;
                        if (++it > 3000000) break;
                        __builtin_amdgcn_s_sleep(1);
                    }
                    const u16* hrd = h0seq + (size_t)(t - 1) * 32768 + hoff;
#pragma unroll
                    for (int kc = 0; kc < 16; kc += 2) {
                        bf16x8 a0 = *(const bf16x8*)(hrd + kc * 2048);
                        bf16x8 a1 = *(const bf16x8*)(hrd + (kc + 1) * 2048);
                        acc0 = __builtin_amdgcn_mfma_f32_16x16x32_bf16(a0, *(const bf16x8*)(&Wh[l16][kc * 32 + quad * 8]), acc0, 0, 0, 0);
                        acc1 = __builtin_amdgcn_mfma_f32_16x16x32_bf16(a0, *(const bf16x8*)(&Wh[16 + l16][kc * 32 + quad * 8]), acc1, 0, 0, 0);
                        acc2 = __builtin_amdgcn_mfma_f32_16x16x32_bf16(a1, *(const bf16x8*)(&Wh[l16][(kc + 1) * 32 + quad * 8]), acc2, 0, 0, 0);
                        acc3 = __builtin_amdgcn_mfma_f32_16x16x32_bf16(a1, *(const bf16x8*)(&Wh[16 + l16][(kc + 1) * 32 + quad * 8]), acc3, 0, 0, 0);
                    }
                }
            } else {
                // combined wait: h0[t] ready (f0 >= t+1) AND h1[t-1] ready (f1 >= t)
                {
                    int it = 0;
                    for (;;) {
                        int a0 = ag_load(pollF0);
                        int a1 = ag_load(pollF1);
                        if (__all((a0 >= t + 1) && (a1 >= t))) break;
                        if (++it > 3000000) break;
                        __builtin_amdgcn_s_sleep(1);
                    }
                }
                const u16* xrow = h0seq + (size_t)t * 32768 + hoff;
#pragma unroll
                for (int kc = 0; kc < 16; kc += 2) {
                    bf16x8 a0 = *(const bf16x8*)(xrow + kc * 2048);
                    bf16x8 a1 = *(const bf16x8*)(xrow + (kc + 1) * 2048);
                    acc0 = __builtin_amdgcn_mfma_f32_16x16x32_bf16(a0, *(const bf16x8*)(&Wx[l16][kc * 32 + quad * 8]), acc0, 0, 0, 0);
                    acc1 = __builtin_amdgcn_mfma_f32_16x16x32_bf16(a0, *(const bf16x8*)(&Wx[16 + l16][kc * 32 + quad * 8]), acc1, 0, 0, 0);
                    acc2 = __builtin_amdgcn_mfma_f32_16x16x32_bf16(a1, *(const bf16x8*)(&Wx[l16][(kc + 1) * 32 + quad * 8]), acc2, 0, 0, 0);
                    acc3 = __builtin_amdgcn_mfma_f32_16x16x32_bf16(a1, *(const bf16x8*)(&Wx[16 + l16][(kc + 1) * 32 + quad * 8]), acc3, 0, 0, 0);
                }
                if (t > 0) {
                    const u16* hrd = h1seq + (size_t)(t - 1) * 32768 + hoff;
#pragma unroll
                    for (int kc = 0; kc < 16; kc += 2) {
                        bf16x8 a0 = *(const bf16x8*)(hrd + kc * 2048);
                        bf16x8 a1 = *(const bf16x8*)(hrd + (kc + 1) * 2048);
                        acc0 = __builtin_amdgcn_mfma_f32_16x16x32_bf16(a0, *(const bf16x8*)(&Wh[l16][kc * 32 + quad * 8]), acc0, 0, 0, 0);
                        acc1 = __builtin_amdgcn_mfma_f32_16x16x32_bf16(a0, *(const bf16x8*)(&Wh[16 + l16][kc * 32 + quad * 8]), acc1, 0, 0, 0);
                        acc2 = __builtin_amdgcn_mfma_f32_16x16x32_bf16(a1, *(const bf16x8*)(&Wh[l16][(kc + 1) * 32 + quad * 8]), acc2, 0, 0, 0);
                        acc3 = __builtin_amdgcn_mfma_f32_16x16x32_bf16(a1, *(const bf16x8*)(&Wh[16 + l16][(kc + 1) * 32 + quad * 8]), acc3, 0, 0, 0);
                    }
                }
            }
            acc0[0] += acc2[0]; acc0[1] += acc2[1]; acc0[2] += acc2[2]; acc0[3] += acc2[3];
            acc1[0] += acc3[0]; acc1[1] += acc3[1]; acc1[2] += acc3[2]; acc1[3] += acc3[3];
            // wave-local z staging (no barrier: same-wave LDS, lgkmcnt only)
#pragma unroll
            for (int r = 0; r < 4; r++) {
                zs[wave][quad * 4 + r][l16]      = acc0[r];
                zs[wave][quad * 4 + r][16 + l16] = acc1[r];
            }
            u16 hb0, hb1;
            {
                float zi0 = zs[wave][bl][jj]      + bia0[0];
                float zf0 = zs[wave][bl][8 + jj]  + bia0[1];
                float zg0 = zs[wave][bl][16 + jj] + bia0[2];
                float zo0 = zs[wave][bl][24 + jj] + bia0[3];
                c0 = sigm(zf0) * c0 + sigm(zi0) * tanhf(zg0);
                float h0v = sigm(zo0) * tanhf(c0);
                float zi1 = zs[wave][bl][jj + 1]      + bia1[0];
                float zf1 = zs[wave][bl][8 + jj + 1]  + bia1[1];
                float zg1 = zs[wave][bl][16 + jj + 1] + bia1[2];
                float zo1 = zs[wave][bl][24 + jj + 1] + bia1[3];
                c1 = sigm(zf1) * c1 + sigm(zi1) * tanhf(zg1);
                float h1v = sigm(zo1) * tanhf(c1);
                hb0 = f2bf(h0v); hb1 = f2bf(h1v);
            }
            if (!layer) {
                // block-major contiguous store: wave writes 256 B (4 full lines)
                llc_store2(h0seq + (size_t)t * 32768 + me * 512 + b * 8 + jj, hb0, hb1);
                __builtin_amdgcn_s_waitcnt(0);
                if (lane == 0) ag_store(pubF, t + 1);
            } else {
                // single drain: both stores in flight, one waitcnt, one publish
                llc_store2(h1seq + (size_t)t * 32768 + me * 512 + b * 8 + jj, hb0, hb1);
                llc_store2(acat + ((size_t)t * 64 + b) * 544 + jbase + jj, hb0, hb1);
                __builtin_amdgcn_s_waitcnt(0);
                if (lane == 0) ag_store(pubF, t + 1);
            }
        }
    } else {
        // =================== trailing scan + inline gate ==================
        const int sb = blk - 128;          // batch
        const int grp = sb >> 4;           // its batch group
        const int f = tid & 31, rg = tid >> 5;
        float m[4][32];
#pragma unroll
        for (int x = 0; x < 4; x++)
            for (int y = 0; y < 32; y++) m[x][y] = 0.f;
        __shared__ float r1s[32], r2s[32], fis[32], u1s[32], u2s[32];
        __shared__ float red[8][32];
        __shared__ float wred[4];
        __shared__ float gpart[4];
        float wg0 = Wg[2 * tid], wg1 = Wg[2 * tid + 1];
        float bgv = bg[0];
        const int* pollS = f1 + grp * 64 + (tid & 63);
        for (int t = 0; t < 512; t++) {
            float pre = 0.f;
            {
                size_t base = ((size_t)t * 64 + sb) * 32;
                if (tid < 32) pre = r1[base + tid];
                else if (tid < 64) pre = r2[base + tid - 32];
                else if (tid < 96) pre = fi[base + tid - 64];
                else if (tid < 128) pre = uu1[base + tid - 96];
                else if (tid < 160) pre = uu2[base + tid - 128];
            }
            if (tid < 64) {   // wait for h1/acat[t] of this batch group (packed line poll)
                int it = 0;
                for (;;) {
                    int a = ag_load(pollS);
                    if (__all(a >= t + 1)) break;
                    if (++it > 3000000) break;
                    __builtin_amdgcn_s_sleep(1);
                }
            }
            __syncthreads();
            if (tid < 32) r1s[tid] = pre;
            else if (tid < 64) r2s[tid - 32] = pre;
            else if (tid < 96) fis[tid - 64] = pre;
            else if (tid < 128) u1s[tid - 96] = pre;
            else if (tid < 160) u2s[tid - 128] = pre;
            {
                const u16* hr = acat + ((size_t)t * 64 + sb) * 544;
                u32 hv = *(const u32*)(hr + 2 * tid);
                float gp = bf2f((u16)hv) * wg0 + bf2f((u16)(hv >> 16)) * wg1;
                for (int mk = 1; mk < 64; mk <<= 1) gp += __shfl_xor(gp, mk, 64);
                if ((tid & 63) == 0) gpart[tid >> 6] = gp;
            }
            __syncthreads();
            float gsh = sigm(gpart[0] + gpart[1] + gpart[2] + gpart[3] + bgv + 1.0f);
            float p = 0.f;
#pragma unroll
            for (int rl = 0; rl < 4; rl++) {
                float s = 0.f;
                for (int ti = 0; ti < 32; ti++) s += r2s[ti] * m[rl][ti];
                p += r1s[rg * 4 + rl] * s;
            }
            red[rg][f] = p;
            __syncthreads();
            float prev = 0.f;
#pragma unroll
            for (int g = 0; g < 8; g++) prev += red[g][f];
            float curo = gsh * (fis[f] - prev) * (1.0f / 32.0f);
            float nsq = 0.f;
#pragma unroll
            for (int rl = 0; rl < 4; rl++) {
                float a = r1s[rg * 4 + rl] * curo;
                for (int ti = 0; ti < 32; ti++) {
                    m[rl][ti] += a * r2s[ti];
                    nsq += m[rl][ti] * m[rl][ti];
                }
            }
            for (int mk = 1; mk < 64; mk <<= 1) nsq += __shfl_xor(nsq, mk, 64);
            __syncthreads();
            if ((tid & 63) == 0) wred[tid >> 6] = nsq;
            __syncthreads();
            float nrm = sqrtf(wred[0] + wred[1] + wred[2] + wred[3]);
            float sc = nrm > 1.0f ? 1.0f / nrm : 1.0f;   // relu(nrm-1)+1 == max(nrm,1)
            float rp = 0.f;
#pragma unroll
            for (int rl = 0; rl < 4; rl++) {
                float s = 0.f;
                for (int ti = 0; ti < 32; ti++) {
                    m[rl][ti] *= sc;
                    s += m[rl][ti] * u2s[ti];
                }
                rp += u1s[rg * 4 + rl] * s;
            }
            red[rg][f] = rp;
            __syncthreads();
            float rv = 0.f;
#pragma unroll
            for (int g = 0; g < 8; g++) rv += red[g][f];
            float mean = rv;
            for (int mk = 1; mk < 32; mk <<= 1) mean += __shfl_xor(mean, mk, 32);
            mean *= (1.0f / 32.0f);
            float d = rv - mean;
            float var = d * d;
            for (int mk = 1; mk < 32; mk <<= 1) var += __shfl_xor(var, mk, 32);
            var *= (1.0f / 32.0f);
            if (tid < 32) {
                float y = d * rsqrtf(var + 1e-5f);
                llc_store_u16(acat + ((size_t)t * 64 + sb) * 544 + 512 + f, f2bf(y));
            }
            __syncthreads();
        }
    }
}

// ---------------------------------------------------------------------------
extern "C" void kernel_launch(void* const* d_in, const int* in_sizes, int n_in,
                              void* d_out, int out_size, void* d_ws, size_t ws_size,
                              hipStream_t stream)
{
    (void)in_sizes; (void)n_in; (void)out_size; (void)ws_size;
    const int*   tokens = (const int*)d_in[0];
    const float* embW  = (const float*)d_in[1];
    const float* Wih0  = (const float*)d_in[2];
    const float* Whh0  = (const float*)d_in[3];
    const float* bih0  = (const float*)d_in[4];
    const float* bhh0  = (const float*)d_in[5];
    const float* Wih1  = (const float*)d_in[6];
    const float* Whh1  = (const float*)d_in[7];
    const float* bih1  = (const float*)d_in[8];
    const float* bhh1  = (const float*)d_in[9];
    const float* Wpi   = (const float*)d_in[10];
    const float* bpi   = (const float*)d_in[11];
    const float* Wq    = (const float*)d_in[12];
    const float* bq    = (const float*)d_in[13];
    const float* Wk    = (const float*)d_in[14];
    const float* bk    = (const float*)d_in[15];
    const float* Wv    = (const float*)d_in[16];
    const float* bv    = (const float*)d_in[17];
    const float* lng   = (const float*)d_in[18];
    const float* lnb   = (const float*)d_in[19];
    const float* Wm1   = (const float*)d_in[20];
    const float* bm1   = (const float*)d_in[21];
    const float* Wm2   = (const float*)d_in[22];
    const float* bm2   = (const float*)d_in[23];
    const float* Wbind = (const float*)d_in[24];
    const float* bbind = (const float*)d_in[25];
    const float* Wreas = (const float*)d_in[26];
    const float* breas = (const float*)d_in[27];
    const float* Wsp   = (const float*)d_in[28];
    const float* bsp   = (const float*)d_in[29];
    const float* Wg    = (const float*)d_in[30];
    const float* bg    = (const float*)d_in[31];
    const float* Wout  = (const float*)d_in[32];
    const float* bout  = (const float*)d_in[33];

    char* ws = (char*)d_ws;
    size_t off = 0;
    auto alloc = [&](size_t bytes) { size_t o = off; off += (bytes + 255) & ~(size_t)255; return o; };
    int*  flags  = (int*)(ws + alloc(16384 * 4));   // f0 @0, f1 @256 (packed)
    u16*  emb    = (u16*)(ws + alloc(32768ull * 256 * 2));
    u16*  dec    = (u16*)(ws + alloc(32768ull * 192 * 2));
    u16*  initb  = (u16*)(ws + alloc(32768ull * 96 * 2));
    u16*  initr  = (u16*)(ws + alloc(32768ull * 64 * 2));
    u16*  acat   = (u16*)(ws + alloc(32768ull * 544 * 2));
    u16*  h0seq  = (u16*)(ws + alloc(512ull * 64 * 512 * 2));
    u16*  h1seq  = (u16*)(ws + alloc(512ull * 64 * 512 * 2));
    float* role1 = (float*)(ws + alloc(32768ull * 32 * 4));
    float* role2 = (float*)(ws + alloc(32768ull * 32 * 4));
    float* fill  = (float*)(ws + alloc(32768ull * 32 * 4));
    float* u1v   = (float*)(ws + alloc(32768ull * 32 * 4));
    float* u2v   = (float*)(ws + alloc(32768ull * 32 * 4));
    u16* Wx0b  = (u16*)(ws + alloc(2048ull * 256 * 2));
    u16* Wh0b  = (u16*)(ws + alloc(2048ull * 512 * 2));
    u16* Wx1b  = (u16*)(ws + alloc(2048ull * 512 * 2));
    u16* Wh1b  = (u16*)(ws + alloc(2048ull * 512 * 2));
    u16* Wpib  = (u16*)(ws + alloc(192ull * 256 * 2));
    u16* Wbindb = (u16*)(ws + alloc(96ull * 192 * 2));
    u16* Wreasb = (u16*)(ws + alloc(64ull * 192 * 2));
    u16* Woutb  = (u16*)(ws + alloc(128ull * 544 * 2));

    hipMemsetAsync(flags, 0, 16384 * 4, stream);
    {
        Cvt8 c;
        const float* s[8] = {Wih0, Whh0, Wih1, Whh1, Wpi, Wbind, Wreas, Wout};
        u16* d[8] = {Wx0b, Wh0b, Wx1b, Wh1b, Wpib, Wbindb, Wreasb, Woutb};
        int n[8] = {2048 * 256, 2048 * 512, 2048 * 512, 2048 * 512,
                    192 * 256, 96 * 192, 64 * 192, 128 * 544};
        int acc = 0;
        for (int k = 0; k < 8; k++) { c.s[k] = s[k]; c.d[k] = d[k]; c.off4[k] = acc; acc += n[k] / 4; }
        c.off4[8] = acc;
        k_f2b8<<<(acc + 255) / 256, 256, 0, stream>>>(c);
    }
    k_embed<<<4096, 256, 0, stream>>>(tokens, embW, emb);
    k_gemm_bt<<<dim3(256, 2), 256, 0, stream>>>(emb, 256, Wpib, dec, nullptr, 192, bpi, nullptr, 192, 256);
    k_gemm_bt<<<dim3(256, 1), 256, 0, stream>>>(dec, 192, Wbindb, initb, nullptr, 96, bbind, nullptr, 96, 192);
    k_gemm_bt<<<dim3(256, 1), 256, 0, stream>>>(dec, 192, Wreasb, initr, nullptr, 64, breas, nullptr, 64, 192);
    // slot attention (must precede mega: scan consumes its outputs)
    k_slot<3><<<4096, 256, 0, stream>>>(dec, initb, Wq, bq, Wk, bk, Wv, bv, lng, lnb,
                                        Wm1, bm1, Wm2, bm2, Wsp, bsp, role1, role2, fill);
    k_slot<2><<<4096, 256, 0, stream>>>(dec, initr, Wq, bq, Wk, bk, Wv, bv, lng, lnb,
                                        Wm1, bm1, Wm2, bm2, Wsp, bsp, u1v, u2v, nullptr);
    // fused LSTM(2 layers) + trailing scan/gate, wave-autonomous sync
    k_mega<<<192, 256, 0, stream>>>(emb, Wx0b, Wh0b, Wx1b, Wh1b,
                                    bih0, bhh0, bih1, bhh1,
                                    h0seq, h1seq, acat, flags,
                                    role1, role2, fill, u1v, u2v, Wg, bg);
    // out = acat @ Wout^T + bout  (fp32 output)
    k_gemm_bt<<<dim3(256, 1), 256, 0, stream>>>(acat, 544, Woutb, nullptr, (float*)d_out, 128, bout, nullptr, 128, 544);
}

// Round 5
// 3564.944 us; speedup vs baseline: 1.8633x; 1.8633x over previous
//
#include <hip/hip_runtime.h>

typedef unsigned short u16;
typedef unsigned int u32;
typedef unsigned long long u64;
typedef __bf16 bf16x8 __attribute__((ext_vector_type(8)));
typedef float f32x4 __attribute__((ext_vector_type(4)));

__device__ __forceinline__ float bf2f(u16 u) { return __uint_as_float(((u32)u) << 16); }
__device__ __forceinline__ u16 f2bf(float f) {
    u32 u = __float_as_uint(f);
    u32 r = (u + 0x7FFFu + ((u >> 16) & 1u)) >> 16;
    return (u16)r;
}
__device__ __forceinline__ float sigm(float x) { return 1.0f / (1.0f + __expf(-x)); }
__device__ __forceinline__ float elu1(float x) { return x > 0.0f ? x + 1.0f : __expf(x); }

// agent-scope (LLC) atomics — HW-validated cross-XCD path (R5/R7)
__device__ __forceinline__ int ag_load(const int* p) {
    return __hip_atomic_load(p, __ATOMIC_RELAXED, __HIP_MEMORY_SCOPE_AGENT);
}
__device__ __forceinline__ void ag_store(int* p, int v) {
    __hip_atomic_store(p, v, __ATOMIC_RELAXED, __HIP_MEMORY_SCOPE_AGENT);
}
__device__ __forceinline__ void llc_store2(u16* p, u16 a, u16 b) {
    u32 v = (u32)a | ((u32)b << 16);
    __hip_atomic_store((u32*)p, v, __ATOMIC_RELAXED, __HIP_MEMORY_SCOPE_AGENT);
}
__device__ __forceinline__ void llc_store_u16(u16* p, u16 v) {
    __hip_atomic_store(p, v, __ATOMIC_RELAXED, __HIP_MEMORY_SCOPE_AGENT);
}

// ---------------------------------------------------------------------------
struct Cvt8 { const float* s[8]; u16* d[8]; int off4[9]; };

__global__ __launch_bounds__(256) void k_f2b8(Cvt8 c)
{
    int i = blockIdx.x * 256 + threadIdx.x;
    if (i >= c.off4[8]) return;
    int k = 0;
#pragma unroll
    for (int q = 1; q < 8; q++) if (i >= c.off4[q]) k = q;
    int j = i - c.off4[k];
    float4 v = ((const float4*)c.s[k])[j];
    ushort4 o;
    o.x = f2bf(v.x); o.y = f2bf(v.y); o.z = f2bf(v.z); o.w = f2bf(v.w);
    ((ushort4*)c.d[k])[j] = o;
}

// ---------------------------------------------------------------------------
__global__ __launch_bounds__(256) void k_embed(const int* __restrict__ tok,
                                               const float* __restrict__ W,
                                               u16* __restrict__ out)
{
    int c = blockIdx.x * 256 + threadIdx.x;
    int row = c >> 5, cc = (c & 31) * 8;
    int t = tok[row];
    const float* src = W + (size_t)t * 256 + cc;
    u16 tmp[8];
#pragma unroll
    for (int k = 0; k < 8; k++) tmp[k] = f2bf(src[k]);
    *(uint4*)(out + (size_t)row * 256 + cc) = *(uint4*)tmp;
}

// ---------------------------------------------------------------------------
// GEMM:  C[M,N] = A[M,K](bf16, lda) * B[N,K]^T(bf16) + bias. 128x128 tile.
// ---------------------------------------------------------------------------
__global__ __launch_bounds__(256) void k_gemm_bt(
    const u16* __restrict__ A, int lda,
    const u16* __restrict__ B,
    u16* __restrict__ Cb, float* __restrict__ Cf, int ldc,
    const float* __restrict__ bias1, const float* __restrict__ bias2,
    int N, int K)
{
    __shared__ u16 As[128][40];
    __shared__ u16 Bs[128][40];
    const int tid = threadIdx.x;
    const int m0 = blockIdx.x * 128, n0 = blockIdx.y * 128;
    const int wave = tid >> 6, lane = tid & 63;
    const int wm = wave & 1, wn = wave >> 1;
    const int quad = lane >> 4, l16 = lane & 15;
    f32x4 acc[4][4] = {};
    for (int k0 = 0; k0 < K; k0 += 32) {
        __syncthreads();
#pragma unroll
        for (int i = 0; i < 2; i++) {
            int c = tid + i * 256, row = c >> 2, cc = (c & 3) * 8;
            *(uint4*)(&As[row][cc]) = *(const uint4*)(A + (size_t)(m0 + row) * lda + k0 + cc);
            uint4 d = {0, 0, 0, 0};
            if (n0 + row < N) d = *(const uint4*)(B + (size_t)(n0 + row) * K + k0 + cc);
            *(uint4*)(&Bs[row][cc]) = d;
        }
        __syncthreads();
        bf16x8 af[4], bfm[4];
#pragma unroll
        for (int x = 0; x < 4; x++) {
            af[x]  = *(const bf16x8*)(&As[wm * 64 + x * 16 + l16][quad * 8]);
            bfm[x] = *(const bf16x8*)(&Bs[wn * 64 + x * 16 + l16][quad * 8]);
        }
#pragma unroll
        for (int mi = 0; mi < 4; mi++)
#pragma unroll
            for (int ni = 0; ni < 4; ni++)
                acc[mi][ni] = __builtin_amdgcn_mfma_f32_16x16x32_bf16(af[mi], bfm[ni], acc[mi][ni], 0, 0, 0);
    }
#pragma unroll
    for (int ni = 0; ni < 4; ni++) {
        int col = n0 + wn * 64 + ni * 16 + l16;
        if (col < N) {
            float bv = 0.f;
            if (bias1) bv += bias1[col];
            if (bias2) bv += bias2[col];
#pragma unroll
            for (int mi = 0; mi < 4; mi++) {
                int r0 = m0 + wm * 64 + mi * 16 + quad * 4;
#pragma unroll
                for (int r = 0; r < 4; r++) {
                    float v = acc[mi][ni][r] + bv;
                    if (Cb) Cb[(size_t)(r0 + r) * ldc + col] = f2bf(v);
                    else    Cf[(size_t)(r0 + r) * ldc + col] = v;
                }
            }
        }
    }
}

// ---------------------------------------------------------------------------
// Slot attention (standalone, R5-proven). 8 positions/block.
// ---------------------------------------------------------------------------
template <int NSLOT>
__global__ __launch_bounds__(256) void k_slot(
    const u16* __restrict__ dec, const u16* __restrict__ initp,
    const float* __restrict__ Wq, const float* __restrict__ bq,
    const float* __restrict__ Wk, const float* __restrict__ bk,
    const float* __restrict__ Wv, const float* __restrict__ bv,
    const float* __restrict__ lng, const float* __restrict__ lnb,
    const float* __restrict__ Wm1, const float* __restrict__ bm1,
    const float* __restrict__ Wm2, const float* __restrict__ bm2,
    const float* __restrict__ Wsp, const float* __restrict__ bsp,
    float* __restrict__ o1, float* __restrict__ o2, float* __restrict__ o3)
{
    __shared__ float WqT[32][33], WkT[64][33], WvT[64][33], Wm1T[32][65], Wm2T[64][33], WspT[64][33];
    __shared__ float bq_s[32], bk_s[32], bv_s[32], bm1_s[64], bm2_s[32], bsp_s[32], g_s[32], be_s[32];
    __shared__ u16 xbuf[8][192];
    __shared__ float slots[8][3][32], initl[8][3][32], kk[8][3][32], vv[8][3][32], qq[8][3][32];
    __shared__ float att[8][3][4];
    __shared__ float ubuf[8][32];
    __shared__ float hid[8][64];
    const int tid = threadIdx.x;
    for (int i = tid; i < 1024; i += 256) { int o = i >> 5, c = i & 31; WqT[c][o] = Wq[o * 32 + c]; }
    for (int i = tid; i < 2048; i += 256) {
        int o6 = i >> 6, c6 = i & 63;
        WkT[c6][o6]  = Wk[o6 * 64 + c6];
        WvT[c6][o6]  = Wv[o6 * 64 + c6];
        Wm2T[c6][o6] = Wm2[o6 * 64 + c6];
        WspT[c6][o6] = Wsp[o6 * 64 + c6];
        int o5 = i >> 5, c5 = i & 31;
        Wm1T[c5][o5] = Wm1[o5 * 32 + c5];
    }
    if (tid < 32) {
        bq_s[tid] = bq[tid]; bk_s[tid] = bk[tid]; bv_s[tid] = bv[tid];
        bm2_s[tid] = bm2[tid]; bsp_s[tid] = bsp[tid];
        g_s[tid] = lng[tid]; be_s[tid] = lnb[tid];
    }
    if (tid < 64) bm1_s[tid] = bm1[tid];
    const int p = tid >> 5, l = tid & 31;
    const size_t row = (size_t)blockIdx.x * 8 + p;
    for (int i = l; i < 192; i += 32) xbuf[p][i] = dec[row * 192 + i];
    __syncthreads();
#pragma unroll
    for (int i = 0; i < 3; i++) {
        float aK = bk_s[l], aV = bv_s[l];
        for (int c = 0; c < 64; c++) {
            float x = bf2f(xbuf[p][i * 64 + c]);
            aK += x * WkT[c][l];
            aV += x * WvT[c][l];
        }
        kk[p][i][l] = elu1(aK);
        vv[p][i][l] = aV;
    }
#pragma unroll
    for (int j = 0; j < NSLOT; j++) {
        float iv = bf2f(initp[row * (NSLOT * 32) + j * 32 + l]);
        initl[p][j][l] = iv;
        slots[p][j][l] = iv;
    }
    __syncthreads();
    const float rs = 0.17677669529663687f;
    for (int it = 0; it < 3; it++) {
#pragma unroll
        for (int j = 0; j < NSLOT; j++) {
            float a = bq_s[l];
            for (int c = 0; c < 32; c++) a += slots[p][j][c] * WqT[c][l];
            qq[p][j][l] = elu1((a + initl[p][j][l]) * rs);
        }
        __syncthreads();
        if (l < 3 * NSLOT) {
            int i = l / NSLOT, j = l % NSLOT;
            float s = 0.f;
            for (int c = 0; c < 32; c++) s += kk[p][i][c] * qq[p][j][c];
            att[p][i][j] = s;
        }
        __syncthreads();
        if (l < 3) {
            float mx = -1e30f;
            for (int j = 0; j < NSLOT; j++) mx = fmaxf(mx, att[p][l][j]);
            float sm = 0.f, ex[NSLOT];
            for (int j = 0; j < NSLOT; j++) { ex[j] = __expf(att[p][l][j] - mx); sm += ex[j]; }
            for (int j = 0; j < NSLOT; j++) att[p][l][j] = ex[j] / sm + 1e-8f;
        }
        __syncthreads();
        if (l < NSLOT) {
            float s = att[p][0][l] + att[p][1][l] + att[p][2][l];
            float inv = 1.0f / s;
            for (int i = 0; i < 3; i++) att[p][i][l] *= inv;
        }
        __syncthreads();
#pragma unroll
        for (int j = 0; j < NSLOT; j++) {
            float u = att[p][0][j] * vv[p][0][l] + att[p][1][j] * vv[p][1][l] + att[p][2][j] * vv[p][2][l];
            float mean = u;
            for (int mk = 1; mk < 32; mk <<= 1) mean += __shfl_xor(mean, mk, 32);
            mean *= (1.0f / 32.0f);
            float d = u - mean;
            float var = d * d;
            for (int mk = 1; mk < 32; mk <<= 1) var += __shfl_xor(var, mk, 32);
            var *= (1.0f / 32.0f);
            float y = d * rsqrtf(var + 1e-5f) * g_s[l] + be_s[l];
            ubuf[p][l] = y;
            __syncthreads();
#pragma unroll
            for (int oo = 0; oo < 2; oo++) {
                int o = l + oo * 32;
                float a = bm1_s[o];
                for (int c = 0; c < 32; c++) a += ubuf[p][c] * Wm1T[c][o];
                hid[p][o] = fmaxf(a, 0.f);
            }
            __syncthreads();
            float a2 = bm2_s[l];
            for (int c = 0; c < 64; c++) a2 += hid[p][c] * Wm2T[c][l];
            slots[p][j][l] += a2 * (1.0f / 32.0f);
            __syncthreads();
        }
    }
    float pj[NSLOT];
#pragma unroll
    for (int j = 0; j < NSLOT; j++) {
        float a = bsp_s[l];
        for (int c = 0; c < 32; c++) a += initl[p][j][c] * WspT[c][l];
        for (int c = 0; c < 32; c++) a += slots[p][j][c] * WspT[32 + c][l];
        pj[j] = a;
    }
    const float e = 1e-6f, me = (float)(1.0 - 2e-6);
    if (NSLOT == 3) {
        o1[row * 32 + l] = tanhf(me * pj[0] + e * pj[1] + e * pj[2]);
        o2[row * 32 + l] = tanhf(e * pj[0] + me * pj[1] + e * pj[2]);
        o3[row * 32 + l] = tanhf(e * pj[0] + e * pj[1] + me * pj[2]);
    } else {
        o1[row * 32 + l] = tanhf(me * pj[0] + e * pj[1]);
        o2[row * 32 + l] = tanhf(e * pj[0] + me * pj[1]);
    }
}

// ---------------------------------------------------------------------------
// Mega kernel: 193 blocks. Wave-autonomous LSTM; block-major h layout (R10).
// R12 sync: R10's flag fabric UNCHANGED on the write side (per-(group,block)
// stride-16 lines, parallel plain agent stores — R8/R11 lesson: any multi-
// writer line serializes at the LLC). Read side decoupled via AGGREGATOR:
//   block 192, wave g: sole poller of group g's 64-line f0/f1/f1s gathers;
//   publishes monotone epochs ep0[g]/ep1[g]/ep1s[g] = min over blocks
//   (single-writer lines). Consumers poll ONE uniform line (64 same-address
//   lanes -> 1 LLC transaction) instead of a 64-line gather: poll LLC demand
//   drops ~64x (was ~3.9 KB/cy from ~576 spinning waves — LLC-saturating;
//   that congestion stretched flag-detect to 1-2 us and queued every
//   critical-path access behind poll gathers).
//   flags: f0 @0, f1 @4096, f1s @8192, epochs @12288 (12 lines)
// ---------------------------------------------------------------------------
__global__ __launch_bounds__(256) void k_mega(
    const u16* __restrict__ emb,
    const u16* __restrict__ Wx0, const u16* __restrict__ Wh0,
    const u16* __restrict__ Wx1, const u16* __restrict__ Wh1,
    const float* __restrict__ bi0, const float* __restrict__ bh0,
    const float* __restrict__ bi1, const float* __restrict__ bh1,
    u16* __restrict__ h0seq,        // [512][64][64][8] block-major
    u16* __restrict__ h1seq,        // [512][64][64][8] block-major
    u16* __restrict__ acat,         // [32768][544]; cols 0..511 h1, 512.. scan out
    int* __restrict__ flags,
    const float* __restrict__ r1, const float* __restrict__ r2,
    const float* __restrict__ fi, const float* __restrict__ uu1,
    const float* __restrict__ uu2,
    const float* __restrict__ Wg, const float* __restrict__ bg)
{
    const int tid = threadIdx.x;
    const int blk = blockIdx.x;
    int* f0  = flags;
    int* f1  = flags + 4096;
    int* f1s = flags + 8192;
    int* eps = flags + 12288;   // ep0[g]=eps+g*16, ep1[g]=eps+(4+g)*16, ep1s[g]=eps+(8+g)*16

    if (blk < 128) {
        // =================== wave-autonomous LSTM ======================
        __shared__ u16 Wx[32][528];
        __shared__ u16 Wh[32][528];
        __shared__ float zs[4][16][33];
        const int layer = blk >> 6;
        const int me = blk & 63;
        const int jbase = me * 8;
        const int Kx = layer ? 512 : 256;
        const u16* Wxp = layer ? Wx1 : Wx0;
        const u16* Whp = layer ? Wh1 : Wh0;
        const float* bi = layer ? bi1 : bi0;
        const float* bh = layer ? bh1 : bh0;
#pragma unroll
        for (int i = 0; i < 8; i++) {
            int c = tid + i * 256;
            int row = c >> 6, cc = (c & 63) * 8;
            int grow = (row >> 3) * 512 + jbase + (row & 7);
            *(uint4*)(&Wh[row][cc]) = *(const uint4*)(Whp + (size_t)grow * 512 + cc);
        }
        {
            int cpr = Kx >> 3;
            int iters = (32 * cpr) >> 8;
            for (int i = 0; i < iters; i++) {
                int c = tid + i * 256;
                int row = c / cpr, cc = (c % cpr) * 8;
                int grow = (row >> 3) * 512 + jbase + (row & 7);
                *(uint4*)(&Wx[row][cc]) = *(const uint4*)(Wxp + (size_t)grow * Kx + cc);
            }
        }
        const int wave = tid >> 6, lane = tid & 63;
        const int quad = lane >> 4, l16 = lane & 15;
        const int m = wave * 16 + l16;       // global batch row for MFMA A-load
        const int bl = lane >> 2;            // local batch (0..15)
        const int b = wave * 16 + bl;        // global batch for elementwise
        const int jj = (lane & 3) * 2;       // local col pair
        const int hoff = quad * 512 + m * 8; // block-major read offset (elements)
        float bia0[4], bia1[4];
#pragma unroll
        for (int g = 0; g < 4; g++) {
            bia0[g] = bi[g * 512 + jbase + jj]     + bh[g * 512 + jbase + jj];
            bia1[g] = bi[g * 512 + jbase + jj + 1] + bh[g * 512 + jbase + jj + 1];
        }
        const int* ep0w = eps + wave * 16;        // uniform single-line polls
        const int* ep1w = eps + (4 + wave) * 16;
        int* pubF = (layer ? f1 : f0) + (wave * 64 + me) * 16;   // own line (parallel)
        float c0 = 0.f, c1 = 0.f;
        __syncthreads();   // Wx/Wh staged; last barrier before the loop
        for (int t = 0; t < 512; t++) {
            f32x4 acc0 = {}, acc1 = {};
            if (!layer) {
                // x-part (emb, independent of flags)
                const u16* xrow = emb + ((size_t)t * 64 + m) * 256;
#pragma unroll
                for (int kc = 0; kc < 8; kc++) {
                    bf16x8 a  = *(const bf16x8*)(xrow + kc * 32 + quad * 8);
                    bf16x8 w0 = *(const bf16x8*)(&Wx[l16][kc * 32 + quad * 8]);
                    bf16x8 w1 = *(const bf16x8*)(&Wx[16 + l16][kc * 32 + quad * 8]);
                    acc0 = __builtin_amdgcn_mfma_f32_16x16x32_bf16(a, w0, acc0, 0, 0, 0);
                    acc1 = __builtin_amdgcn_mfma_f32_16x16x32_bf16(a, w1, acc1, 0, 0, 0);
                }
                if (t > 0) {   // wait for group-w h0[t-1]: ep0 >= t
                    int it = 0;
                    for (;;) {
                        int a = ag_load(ep0w);
                        if (a >= t) break;
                        if (++it > 3000000) break;
                        __builtin_amdgcn_s_sleep(1);
                    }
                    const u16* hrd = h0seq + (size_t)(t - 1) * 32768 + hoff;
#pragma unroll
                    for (int kc = 0; kc < 16; kc++) {
                        bf16x8 a  = *(const bf16x8*)(hrd + kc * 2048);
                        bf16x8 w0 = *(const bf16x8*)(&Wh[l16][kc * 32 + quad * 8]);
                        bf16x8 w1 = *(const bf16x8*)(&Wh[16 + l16][kc * 32 + quad * 8]);
                        acc0 = __builtin_amdgcn_mfma_f32_16x16x32_bf16(a, w0, acc0, 0, 0, 0);
                        acc1 = __builtin_amdgcn_mfma_f32_16x16x32_bf16(a, w1, acc1, 0, 0, 0);
                    }
                }
            } else {
                // wait for h0[t]: ep0 >= t+1, then x-part
                {
                    int it = 0;
                    for (;;) {
                        int a = ag_load(ep0w);
                        if (a >= t + 1) break;
                        if (++it > 3000000) break;
                        __builtin_amdgcn_s_sleep(1);
                    }
                }
                const u16* xrow = h0seq + (size_t)t * 32768 + hoff;
#pragma unroll
                for (int kc = 0; kc < 16; kc++) {
                    bf16x8 a  = *(const bf16x8*)(xrow + kc * 2048);
                    bf16x8 w0 = *(const bf16x8*)(&Wx[l16][kc * 32 + quad * 8]);
                    bf16x8 w1 = *(const bf16x8*)(&Wx[16 + l16][kc * 32 + quad * 8]);
                    acc0 = __builtin_amdgcn_mfma_f32_16x16x32_bf16(a, w0, acc0, 0, 0, 0);
                    acc1 = __builtin_amdgcn_mfma_f32_16x16x32_bf16(a, w1, acc1, 0, 0, 0);
                }
                if (t > 0) {   // wait for group-w h1[t-1]: ep1 >= t
                    int it = 0;
                    for (;;) {
                        int a = ag_load(ep1w);
                        if (a >= t) break;
                        if (++it > 3000000) break;
                        __builtin_amdgcn_s_sleep(1);
                    }
                    const u16* hrd = h1seq + (size_t)(t - 1) * 32768 + hoff;
#pragma unroll
                    for (int kc = 0; kc < 16; kc++) {
                        bf16x8 a  = *(const bf16x8*)(hrd + kc * 2048);
                        bf16x8 w0 = *(const bf16x8*)(&Wh[l16][kc * 32 + quad * 8]);
                        bf16x8 w1 = *(const bf16x8*)(&Wh[16 + l16][kc * 32 + quad * 8]);
                        acc0 = __builtin_amdgcn_mfma_f32_16x16x32_bf16(a, w0, acc0, 0, 0, 0);
                        acc1 = __builtin_amdgcn_mfma_f32_16x16x32_bf16(a, w1, acc1, 0, 0, 0);
                    }
                }
            }
            // wave-local z staging (no barrier: same-wave LDS, lgkmcnt only)
#pragma unroll
            for (int r = 0; r < 4; r++) {
                zs[wave][quad * 4 + r][l16]      = acc0[r];
                zs[wave][quad * 4 + r][16 + l16] = acc1[r];
            }
            u16 hb0, hb1;
            {
                float zi0 = zs[wave][bl][jj]      + bia0[0];
                float zf0 = zs[wave][bl][8 + jj]  + bia0[1];
                float zg0 = zs[wave][bl][16 + jj] + bia0[2];
                float zo0 = zs[wave][bl][24 + jj] + bia0[3];
                c0 = sigm(zf0) * c0 + sigm(zi0) * tanhf(zg0);
                float h0v = sigm(zo0) * tanhf(c0);
                float zi1 = zs[wave][bl][jj + 1]      + bia1[0];
                float zf1 = zs[wave][bl][8 + jj + 1]  + bia1[1];
                float zg1 = zs[wave][bl][16 + jj + 1] + bia1[2];
                float zo1 = zs[wave][bl][24 + jj + 1] + bia1[3];
                c1 = sigm(zf1) * c1 + sigm(zi1) * tanhf(zg1);
                float h1v = sigm(zo1) * tanhf(c1);
                hb0 = f2bf(h0v); hb1 = f2bf(h1v);
            }
            if (!layer) {
                // block-major contiguous store: wave writes 256 B (4 full lines)
                llc_store2(h0seq + (size_t)t * 32768 + me * 512 + b * 8 + jj, hb0, hb1);
                __builtin_amdgcn_s_waitcnt(0);
                if (lane == 0) ag_store(pubF, t + 1);
            } else {
                llc_store2(h1seq + (size_t)t * 32768 + me * 512 + b * 8 + jj, hb0, hb1);
                __builtin_amdgcn_s_waitcnt(0);   // drain recurrence copy only
                if (lane == 0) ag_store(pubF, t + 1);
                // row-major copy for scan gate + final GEMM (off critical path)
                llc_store2(acat + ((size_t)t * 64 + b) * 544 + jbase + jj, hb0, hb1);
                __builtin_amdgcn_s_waitcnt(0);
                if (lane == 0) ag_store(f1s + (wave * 64 + me) * 16, t + 1);
            }
        }
    } else if (blk < 192) {
        // =================== trailing scan + inline gate ==================
        const int sb = blk - 128;          // batch
        const int grp = sb >> 4;           // its batch group
        const int f = tid & 31, rg = tid >> 5;
        float m[4][32];
#pragma unroll
        for (int x = 0; x < 4; x++)
            for (int y = 0; y < 32; y++) m[x][y] = 0.f;
        __shared__ float r1s[32], r2s[32], fis[32], u1s[32], u2s[32];
        __shared__ float red[8][32];
        __shared__ float wred[4];
        __shared__ float gpart[4];
        float wg0 = Wg[2 * tid], wg1 = Wg[2 * tid + 1];
        float bgv = bg[0];
        const int* epsg = eps + (8 + grp) * 16;
        for (int t = 0; t < 512; t++) {
            float pre = 0.f;
            {
                size_t base = ((size_t)t * 64 + sb) * 32;
                if (tid < 32) pre = r1[base + tid];
                else if (tid < 64) pre = r2[base + tid - 32];
                else if (tid < 96) pre = fi[base + tid - 64];
                else if (tid < 128) pre = uu1[base + tid - 96];
                else if (tid < 160) pre = uu2[base + tid - 128];
            }
            if (tid < 64) {   // wait for acat h1[t] of this group: ep1s >= t+1
                int it = 0;
                for (;;) {
                    int a = ag_load(epsg);
                    if (a >= t + 1) break;
                    if (++it > 3000000) break;
                    __builtin_amdgcn_s_sleep(1);
                }
            }
            __syncthreads();
            if (tid < 32) r1s[tid] = pre;
            else if (tid < 64) r2s[tid - 32] = pre;
            else if (tid < 96) fis[tid - 64] = pre;
            else if (tid < 128) u1s[tid - 96] = pre;
            else if (tid < 160) u2s[tid - 128] = pre;
            {
                const u16* hr = acat + ((size_t)t * 64 + sb) * 544;
                u32 hv = *(const u32*)(hr + 2 * tid);
                float gp = bf2f((u16)hv) * wg0 + bf2f((u16)(hv >> 16)) * wg1;
                for (int mk = 1; mk < 64; mk <<= 1) gp += __shfl_xor(gp, mk, 64);
                if ((tid & 63) == 0) gpart[tid >> 6] = gp;
            }
            __syncthreads();
            float gsh = sigm(gpart[0] + gpart[1] + gpart[2] + gpart[3] + bgv + 1.0f);
            float p = 0.f;
#pragma unroll
            for (int rl = 0; rl < 4; rl++) {
                float s = 0.f;
                for (int ti = 0; ti < 32; ti++) s += r2s[ti] * m[rl][ti];
                p += r1s[rg * 4 + rl] * s;
            }
            red[rg][f] = p;
            __syncthreads();
            float prev = 0.f;
#pragma unroll
            for (int g = 0; g < 8; g++) prev += red[g][f];
            float curo = gsh * (fis[f] - prev) * (1.0f / 32.0f);
            float nsq = 0.f;
#pragma unroll
            for (int rl = 0; rl < 4; rl++) {
                float a = r1s[rg * 4 + rl] * curo;
                for (int ti = 0; ti < 32; ti++) {
                    m[rl][ti] += a * r2s[ti];
                    nsq += m[rl][ti] * m[rl][ti];
                }
            }
            for (int mk = 1; mk < 64; mk <<= 1) nsq += __shfl_xor(nsq, mk, 64);
            __syncthreads();
            if ((tid & 63) == 0) wred[tid >> 6] = nsq;
            __syncthreads();
            float nrm = sqrtf(wred[0] + wred[1] + wred[2] + wred[3]);
            float sc = nrm > 1.0f ? 1.0f / nrm : 1.0f;   // relu(nrm-1)+1 == max(nrm,1)
            float rp = 0.f;
#pragma unroll
            for (int rl = 0; rl < 4; rl++) {
                float s = 0.f;
                for (int ti = 0; ti < 32; ti++) {
                    m[rl][ti] *= sc;
                    s += m[rl][ti] * u2s[ti];
                }
                rp += u1s[rg * 4 + rl] * s;
            }
            red[rg][f] = rp;
            __syncthreads();
            float rv = 0.f;
#pragma unroll
            for (int g = 0; g < 8; g++) rv += red[g][f];
            float mean = rv;
            for (int mk = 1; mk < 32; mk <<= 1) mean += __shfl_xor(mean, mk, 32);
            mean *= (1.0f / 32.0f);
            float d = rv - mean;
            float var = d * d;
            for (int mk = 1; mk < 32; mk <<= 1) var += __shfl_xor(var, mk, 32);
            var *= (1.0f / 32.0f);
            if (tid < 32) {
                float y = d * rsqrtf(var + 1e-5f);
                llc_store_u16(acat + ((size_t)t * 64 + sb) * 544 + 512 + f, f2bf(y));
            }
            __syncthreads();
        }
    } else {
        // =================== aggregator (blk 192) ==================
        // Wave g: sole reader of group g's flag lines; publishes min-epochs.
        const int wave = tid >> 6, lane = tid & 63;
        const int* l0 = f0  + (wave * 64 + lane) * 16;
        const int* l1 = f1  + (wave * 64 + lane) * 16;
        const int* l2 = f1s + (wave * 64 + lane) * 16;
        int* ep0 = eps + wave * 16;
        int* ep1 = eps + (4 + wave) * 16;
        int* ep2 = eps + (8 + wave) * 16;
        int e0 = 0, e1 = 0, e2 = 0;
        long it = 0;
        while (e0 < 512 || e1 < 512 || e2 < 512) {
            if (e0 < 512) {
                int v = ag_load(l0);
                for (int mk = 1; mk < 64; mk <<= 1) { int o = __shfl_xor(v, mk, 64); v = v < o ? v : o; }
                if (v > e0) { if (lane == 0) ag_store(ep0, v); e0 = v; }
            }
            if (e1 < 512) {
                int v = ag_load(l1);
                for (int mk = 1; mk < 64; mk <<= 1) { int o = __shfl_xor(v, mk, 64); v = v < o ? v : o; }
                if (v > e1) { if (lane == 0) ag_store(ep1, v); e1 = v; }
            }
            if (e2 < 512) {
                int v = ag_load(l2);
                for (int mk = 1; mk < 64; mk <<= 1) { int o = __shfl_xor(v, mk, 64); v = v < o ? v : o; }
                if (v > e2) { if (lane == 0) ag_store(ep2, v); e2 = v; }
            }
            if (++it > 50000000) break;
        }
    }
}

// ---------------------------------------------------------------------------
extern "C" void kernel_launch(void* const* d_in, const int* in_sizes, int n_in,
                              void* d_out, int out_size, void* d_ws, size_t ws_size,
                              hipStream_t stream)
{
    (void)in_sizes; (void)n_in; (void)out_size; (void)ws_size;
    const int*   tokens = (const int*)d_in[0];
    const float* embW  = (const float*)d_in[1];
    const float* Wih0  = (const float*)d_in[2];
    const float* Whh0  = (const float*)d_in[3];
    const float* bih0  = (const float*)d_in[4];
    const float* bhh0  = (const float*)d_in[5];
    const float* Wih1  = (const float*)d_in[6];
    const float* Whh1  = (const float*)d_in[7];
    const float* bih1  = (const float*)d_in[8];
    const float* bhh1  = (const float*)d_in[9];
    const float* Wpi   = (const float*)d_in[10];
    const float* bpi   = (const float*)d_in[11];
    const float* Wq    = (const float*)d_in[12];
    const float* bq    = (const float*)d_in[13];
    const float* Wk    = (const float*)d_in[14];
    const float* bk    = (const float*)d_in[15];
    const float* Wv    = (const float*)d_in[16];
    const float* bv    = (const float*)d_in[17];
    const float* lng   = (const float*)d_in[18];
    const float* lnb   = (const float*)d_in[19];
    const float* Wm1   = (const float*)d_in[20];
    const float* bm1   = (const float*)d_in[21];
    const float* Wm2   = (const float*)d_in[22];
    const float* bm2   = (const float*)d_in[23];
    const float* Wbind = (const float*)d_in[24];
    const float* bbind = (const float*)d_in[25];
    const float* Wreas = (const float*)d_in[26];
    const float* breas = (const float*)d_in[27];
    const float* Wsp   = (const float*)d_in[28];
    const float* bsp   = (const float*)d_in[29];
    const float* Wg    = (const float*)d_in[30];
    const float* bg    = (const float*)d_in[31];
    const float* Wout  = (const float*)d_in[32];
    const float* bout  = (const float*)d_in[33];

    char* ws = (char*)d_ws;
    size_t off = 0;
    auto alloc = [&](size_t bytes) { size_t o = off; off += (bytes + 255) & ~(size_t)255; return o; };
    int*  flags  = (int*)(ws + alloc(16384 * 4));   // f0, f1, f1s, epochs
    u16*  emb    = (u16*)(ws + alloc(32768ull * 256 * 2));
    u16*  dec    = (u16*)(ws + alloc(32768ull * 192 * 2));
    u16*  initb  = (u16*)(ws + alloc(32768ull * 96 * 2));
    u16*  initr  = (u16*)(ws + alloc(32768ull * 64 * 2));
    u16*  acat   = (u16*)(ws + alloc(32768ull * 544 * 2));
    u16*  h0seq  = (u16*)(ws + alloc(512ull * 64 * 512 * 2));
    u16*  h1seq  = (u16*)(ws + alloc(512ull * 64 * 512 * 2));
    float* role1 = (float*)(ws + alloc(32768ull * 32 * 4));
    float* role2 = (float*)(ws + alloc(32768ull * 32 * 4));
    float* fill  = (float*)(ws + alloc(32768ull * 32 * 4));
    float* u1v   = (float*)(ws + alloc(32768ull * 32 * 4));
    float* u2v   = (float*)(ws + alloc(32768ull * 32 * 4));
    u16* Wx0b  = (u16*)(ws + alloc(2048ull * 256 * 2));
    u16* Wh0b  = (u16*)(ws + alloc(2048ull * 512 * 2));
    u16* Wx1b  = (u16*)(ws + alloc(2048ull * 512 * 2));
    u16* Wh1b  = (u16*)(ws + alloc(2048ull * 512 * 2));
    u16* Wpib  = (u16*)(ws + alloc(192ull * 256 * 2));
    u16* Wbindb = (u16*)(ws + alloc(96ull * 192 * 2));
    u16* Wreasb = (u16*)(ws + alloc(64ull * 192 * 2));
    u16* Woutb  = (u16*)(ws + alloc(128ull * 544 * 2));

    hipMemsetAsync(flags, 0, 16384 * 4, stream);
    {
        Cvt8 c;
        const float* s[8] = {Wih0, Whh0, Wih1, Whh1, Wpi, Wbind, Wreas, Wout};
        u16* d[8] = {Wx0b, Wh0b, Wx1b, Wh1b, Wpib, Wbindb, Wreasb, Woutb};
        int n[8] = {2048 * 256, 2048 * 512, 2048 * 512, 2048 * 512,
                    192 * 256, 96 * 192, 64 * 192, 128 * 544};
        int acc = 0;
        for (int k = 0; k < 8; k++) { c.s[k] = s[k]; c.d[k] = d[k]; c.off4[k] = acc; acc += n[k] / 4; }
        c.off4[8] = acc;
        k_f2b8<<<(acc + 255) / 256, 256, 0, stream>>>(c);
    }
    k_embed<<<4096, 256, 0, stream>>>(tokens, embW, emb);
    k_gemm_bt<<<dim3(256, 2), 256, 0, stream>>>(emb, 256, Wpib, dec, nullptr, 192, bpi, nullptr, 192, 256);
    k_gemm_bt<<<dim3(256, 1), 256, 0, stream>>>(dec, 192, Wbindb, initb, nullptr, 96, bbind, nullptr, 96, 192);
    k_gemm_bt<<<dim3(256, 1), 256, 0, stream>>>(dec, 192, Wreasb, initr, nullptr, 64, breas, nullptr, 64, 192);
    // slot attention (must precede mega: scan consumes its outputs)
    k_slot<3><<<4096, 256, 0, stream>>>(dec, initb, Wq, bq, Wk, bk, Wv, bv, lng, lnb,
                                        Wm1, bm1, Wm2, bm2, Wsp, bsp, role1, role2, fill);
    k_slot<2><<<4096, 256, 0, stream>>>(dec, initr, Wq, bq, Wk, bk, Wv, bv, lng, lnb,
                                        Wm1, bm1, Wm2, bm2, Wsp, bsp, u1v, u2v, nullptr);
    // fused LSTM(2 layers) + trailing scan/gate + aggregator, wave-autonomous sync
    k_mega<<<193, 256, 0, stream>>>(emb, Wx0b, Wh0b, Wx1b, Wh1b,
                                    bih0, bhh0, bih1, bhh1,
                                    h0seq, h1seq, acat, flags,
                                    role1, role2, fill, u1v, u2v, Wg, bg);
    // out = acat @ Wout^T + bout  (fp32 output)
    k_gemm_bt<<<dim3(256, 1), 256, 0, stream>>>(acat, 544, Woutb, nullptr, (float*)d_out, 128, bout, nullptr, 128, 544);
}

// Round 6
// 3276.023 us; speedup vs baseline: 2.0276x; 1.0882x over previous
//
#include <hip/hip_runtime.h>

typedef unsigned short u16;
typedef unsigned int u32;
typedef unsigned long long u64;
typedef __bf16 bf16x8 __attribute__((ext_vector_type(8)));
typedef float f32x4 __attribute__((ext_vector_type(4)));

__device__ __forceinline__ float bf2f(u16 u) { return __uint_as_float(((u32)u) << 16); }
__device__ __forceinline__ u16 f2bf(float f) {
    u32 u = __float_as_uint(f);
    u32 r = (u + 0x7FFFu + ((u >> 16) & 1u)) >> 16;
    return (u16)r;
}
__device__ __forceinline__ float sigm(float x) { return 1.0f / (1.0f + __expf(-x)); }
__device__ __forceinline__ float elu1(float x) { return x > 0.0f ? x + 1.0f : __expf(x); }

// agent-scope (LLC) atomics — HW-validated cross-XCD path (R5/R7)
__device__ __forceinline__ int ag_load(const int* p) {
    return __hip_atomic_load(p, __ATOMIC_RELAXED, __HIP_MEMORY_SCOPE_AGENT);
}
__device__ __forceinline__ void ag_store(int* p, int v) {
    __hip_atomic_store(p, v, __ATOMIC_RELAXED, __HIP_MEMORY_SCOPE_AGENT);
}
__device__ __forceinline__ void ag_storef(float* p, float v) {
    __hip_atomic_store(p, v, __ATOMIC_RELAXED, __HIP_MEMORY_SCOPE_AGENT);
}
__device__ __forceinline__ void llc_store2(u16* p, u16 a, u16 b) {
    u32 v = (u32)a | ((u32)b << 16);
    __hip_atomic_store((u32*)p, v, __ATOMIC_RELAXED, __HIP_MEMORY_SCOPE_AGENT);
}
__device__ __forceinline__ void llc_store_u16(u16* p, u16 v) {
    __hip_atomic_store(p, v, __ATOMIC_RELAXED, __HIP_MEMORY_SCOPE_AGENT);
}

// ---------------------------------------------------------------------------
struct Cvt8 { const float* s[8]; u16* d[8]; int off4[9]; };

__global__ __launch_bounds__(256) void k_f2b8(Cvt8 c)
{
    int i = blockIdx.x * 256 + threadIdx.x;
    if (i >= c.off4[8]) return;
    int k = 0;
#pragma unroll
    for (int q = 1; q < 8; q++) if (i >= c.off4[q]) k = q;
    int j = i - c.off4[k];
    float4 v = ((const float4*)c.s[k])[j];
    ushort4 o;
    o.x = f2bf(v.x); o.y = f2bf(v.y); o.z = f2bf(v.z); o.w = f2bf(v.w);
    ((ushort4*)c.d[k])[j] = o;
}

// ---------------------------------------------------------------------------
__global__ __launch_bounds__(256) void k_embed(const int* __restrict__ tok,
                                               const float* __restrict__ W,
                                               u16* __restrict__ out)
{
    int c = blockIdx.x * 256 + threadIdx.x;
    int row = c >> 5, cc = (c & 31) * 8;
    int t = tok[row];
    const float* src = W + (size_t)t * 256 + cc;
    u16 tmp[8];
#pragma unroll
    for (int k = 0; k < 8; k++) tmp[k] = f2bf(src[k]);
    *(uint4*)(out + (size_t)row * 256 + cc) = *(uint4*)tmp;
}

// ---------------------------------------------------------------------------
// GEMM:  C[M,N] = A[M,K](bf16, lda) * B[N,K]^T(bf16) + bias. 128x128 tile.
// ---------------------------------------------------------------------------
__global__ __launch_bounds__(256) void k_gemm_bt(
    const u16* __restrict__ A, int lda,
    const u16* __restrict__ B,
    u16* __restrict__ Cb, float* __restrict__ Cf, int ldc,
    const float* __restrict__ bias1, const float* __restrict__ bias2,
    int N, int K)
{
    __shared__ u16 As[128][40];
    __shared__ u16 Bs[128][40];
    const int tid = threadIdx.x;
    const int m0 = blockIdx.x * 128, n0 = blockIdx.y * 128;
    const int wave = tid >> 6, lane = tid & 63;
    const int wm = wave & 1, wn = wave >> 1;
    const int quad = lane >> 4, l16 = lane & 15;
    f32x4 acc[4][4] = {};
    for (int k0 = 0; k0 < K; k0 += 32) {
        __syncthreads();
#pragma unroll
        for (int i = 0; i < 2; i++) {
            int c = tid + i * 256, row = c >> 2, cc = (c & 3) * 8;
            *(uint4*)(&As[row][cc]) = *(const uint4*)(A + (size_t)(m0 + row) * lda + k0 + cc);
            uint4 d = {0, 0, 0, 0};
            if (n0 + row < N) d = *(const uint4*)(B + (size_t)(n0 + row) * K + k0 + cc);
            *(uint4*)(&Bs[row][cc]) = d;
        }
        __syncthreads();
        bf16x8 af[4], bfm[4];
#pragma unroll
        for (int x = 0; x < 4; x++) {
            af[x]  = *(const bf16x8*)(&As[wm * 64 + x * 16 + l16][quad * 8]);
            bfm[x] = *(const bf16x8*)(&Bs[wn * 64 + x * 16 + l16][quad * 8]);
        }
#pragma unroll
        for (int mi = 0; mi < 4; mi++)
#pragma unroll
            for (int ni = 0; ni < 4; ni++)
                acc[mi][ni] = __builtin_amdgcn_mfma_f32_16x16x32_bf16(af[mi], bfm[ni], acc[mi][ni], 0, 0, 0);
    }
#pragma unroll
    for (int ni = 0; ni < 4; ni++) {
        int col = n0 + wn * 64 + ni * 16 + l16;
        if (col < N) {
            float bv = 0.f;
            if (bias1) bv += bias1[col];
            if (bias2) bv += bias2[col];
#pragma unroll
            for (int mi = 0; mi < 4; mi++) {
                int r0 = m0 + wm * 64 + mi * 16 + quad * 4;
#pragma unroll
                for (int r = 0; r < 4; r++) {
                    float v = acc[mi][ni][r] + bv;
                    if (Cb) Cb[(size_t)(r0 + r) * ldc + col] = f2bf(v);
                    else    Cf[(size_t)(r0 + r) * ldc + col] = v;
                }
            }
        }
    }
}

// ---------------------------------------------------------------------------
// Shared-memory union: one kernel, three block roles (LSTM / scan / slot).
// ---------------------------------------------------------------------------
struct SmemLstm {
    u16 Wx[32][528];
    u16 Wh[32][528];
    float zs[4][16][33];
};
struct SmemSlot {
    float WqT[32][33], WkT[64][33], WvT[64][33], Wm1T[32][65], Wm2T[64][33], WspT[64][33];
    float bq[32], bk[32], bv[32], bm1[64], bm2[32], bsp[32], g[32], be[32];
    u16 xbuf[8][192];
    float slots[8][3][32], initl[8][3][32], kk[8][3][32], vv[8][3][32], qq[8][3][32];
    float att[8][3][4];
    float ubuf[8][32];
    float hid[8][64];
};
struct SmemScan {
    float r1s[32], r2s[32], fis[32], u1s[32], u2s[32];
    float red[8][32];
    float wred[4];
    float gpart[4];
};
union SmemU {
    SmemLstm l;
    SmemSlot s;
    SmemScan c;
};

// ---------------------------------------------------------------------------
// Slot attention — weights staged ONCE per worker block (R9 restaged per
// unit: ~130x wasted staging). Unit = 8 rows; outputs via agent stores.
// ---------------------------------------------------------------------------
__device__ __forceinline__ void stage_slot_weights(SmemSlot& S, const int tid,
    const float* __restrict__ Wq, const float* __restrict__ bq,
    const float* __restrict__ Wk, const float* __restrict__ bk,
    const float* __restrict__ Wv, const float* __restrict__ bv,
    const float* __restrict__ lng, const float* __restrict__ lnb,
    const float* __restrict__ Wm1, const float* __restrict__ bm1,
    const float* __restrict__ Wm2, const float* __restrict__ bm2,
    const float* __restrict__ Wsp, const float* __restrict__ bsp)
{
    for (int i = tid; i < 1024; i += 256) { int o = i >> 5, c = i & 31; S.WqT[c][o] = Wq[o * 32 + c]; }
    for (int i = tid; i < 2048; i += 256) {
        int o6 = i >> 6, c6 = i & 63;
        S.WkT[c6][o6]  = Wk[o6 * 64 + c6];
        S.WvT[c6][o6]  = Wv[o6 * 64 + c6];
        S.Wm2T[c6][o6] = Wm2[o6 * 64 + c6];
        S.WspT[c6][o6] = Wsp[o6 * 64 + c6];
        int o5 = i >> 5, c5 = i & 31;
        S.Wm1T[c5][o5] = Wm1[o5 * 32 + c5];
    }
    if (tid < 32) {
        S.bq[tid] = bq[tid]; S.bk[tid] = bk[tid]; S.bv[tid] = bv[tid];
        S.bm2[tid] = bm2[tid]; S.bsp[tid] = bsp[tid];
        S.g[tid] = lng[tid]; S.be[tid] = lnb[tid];
    }
    if (tid < 64) S.bm1[tid] = bm1[tid];
}

template <int NSLOT>
__device__ __forceinline__ void slot_unit(
    SmemSlot& S, const int tid, const size_t row0,
    const u16* __restrict__ dec, const u16* __restrict__ initp,
    float* __restrict__ o1, float* __restrict__ o2, float* __restrict__ o3)
{
    const int p = tid >> 5, l = tid & 31;
    const size_t row = row0 + p;
    for (int i = l; i < 192; i += 32) S.xbuf[p][i] = dec[row * 192 + i];
    __syncthreads();
#pragma unroll
    for (int i = 0; i < 3; i++) {
        float aK = S.bk[l], aV = S.bv[l];
        for (int c = 0; c < 64; c++) {
            float x = bf2f(S.xbuf[p][i * 64 + c]);
            aK += x * S.WkT[c][l];
            aV += x * S.WvT[c][l];
        }
        S.kk[p][i][l] = elu1(aK);
        S.vv[p][i][l] = aV;
    }
#pragma unroll
    for (int j = 0; j < NSLOT; j++) {
        float iv = bf2f(initp[row * (NSLOT * 32) + j * 32 + l]);
        S.initl[p][j][l] = iv;
        S.slots[p][j][l] = iv;
    }
    __syncthreads();
    const float rs = 0.17677669529663687f;
    for (int it = 0; it < 3; it++) {
#pragma unroll
        for (int j = 0; j < NSLOT; j++) {
            float a = S.bq[l];
            for (int c = 0; c < 32; c++) a += S.slots[p][j][c] * S.WqT[c][l];
            S.qq[p][j][l] = elu1((a + S.initl[p][j][l]) * rs);
        }
        __syncthreads();
        if (l < 3 * NSLOT) {
            int i = l / NSLOT, j = l % NSLOT;
            float s = 0.f;
            for (int c = 0; c < 32; c++) s += S.kk[p][i][c] * S.qq[p][j][c];
            S.att[p][i][j] = s;
        }
        __syncthreads();
        if (l < 3) {
            float mx = -1e30f;
            for (int j = 0; j < NSLOT; j++) mx = fmaxf(mx, S.att[p][l][j]);
            float sm = 0.f, ex[3];
            for (int j = 0; j < NSLOT; j++) { ex[j] = __expf(S.att[p][l][j] - mx); sm += ex[j]; }
            for (int j = 0; j < NSLOT; j++) S.att[p][l][j] = ex[j] / sm + 1e-8f;
        }
        __syncthreads();
        if (l < NSLOT) {
            float s = S.att[p][0][l] + S.att[p][1][l] + S.att[p][2][l];
            float inv = 1.0f / s;
            for (int i = 0; i < 3; i++) S.att[p][i][l] *= inv;
        }
        __syncthreads();
#pragma unroll
        for (int j = 0; j < NSLOT; j++) {
            float u = S.att[p][0][j] * S.vv[p][0][l] + S.att[p][1][j] * S.vv[p][1][l] + S.att[p][2][j] * S.vv[p][2][l];
            float mean = u;
            for (int mk = 1; mk < 32; mk <<= 1) mean += __shfl_xor(mean, mk, 32);
            mean *= (1.0f / 32.0f);
            float d = u - mean;
            float var = d * d;
            for (int mk = 1; mk < 32; mk <<= 1) var += __shfl_xor(var, mk, 32);
            var *= (1.0f / 32.0f);
            float y = d * rsqrtf(var + 1e-5f) * S.g[l] + S.be[l];
            S.ubuf[p][l] = y;
            __syncthreads();
#pragma unroll
            for (int oo = 0; oo < 2; oo++) {
                int o = l + oo * 32;
                float a = S.bm1[o];
                for (int c = 0; c < 32; c++) a += S.ubuf[p][c] * S.Wm1T[c][o];
                S.hid[p][o] = fmaxf(a, 0.f);
            }
            __syncthreads();
            float a2 = S.bm2[l];
            for (int c = 0; c < 64; c++) a2 += S.hid[p][c] * S.Wm2T[c][l];
            S.slots[p][j][l] += a2 * (1.0f / 32.0f);
            __syncthreads();
        }
    }
    float pj[NSLOT];
#pragma unroll
    for (int j = 0; j < NSLOT; j++) {
        float a = S.bsp[l];
        for (int c = 0; c < 32; c++) a += S.initl[p][j][c] * S.WspT[c][l];
        for (int c = 0; c < 32; c++) a += S.slots[p][j][c] * S.WspT[32 + c][l];
        pj[j] = a;
    }
    const float e = 1e-6f, me = (float)(1.0 - 2e-6);
    if (NSLOT == 3) {
        ag_storef(&o1[row * 32 + l], tanhf(me * pj[0] + e * pj[1] + e * pj[2]));
        ag_storef(&o2[row * 32 + l], tanhf(e * pj[0] + me * pj[1] + e * pj[2]));
        ag_storef(&o3[row * 32 + l], tanhf(e * pj[0] + e * pj[1] + me * pj[2]));
    } else {
        ag_storef(&o1[row * 32 + l], tanhf(me * pj[0] + e * pj[1]));
        ag_storef(&o2[row * 32 + l], tanhf(e * pj[0] + me * pj[1]));
    }
}

// ---------------------------------------------------------------------------
// Mega kernel, 255 blocks (~1 per CU — CU-PARTITIONED roles, not R9's churn):
//   0..127   wave-autonomous LSTM (R10 champion verbatim: block-major h,
//            per-(group,block) flag lines, parallel publishes, 64-line poll)
//   128..191 trailing scan + gate (dual gate: wave0 f1s, wave1 slot progress)
//   192..254 63 persistent slot workers, each on its OWN CU, sweeping 8192
//            units (u%63) in ascending-t order; weights staged once.
// R9's fold failed via CU time-sharing (3.9e8 LDS conflicts on critical
// blocks); here workers never share a CU with LSTM/scan blocks.
// Worker k publishes p[k]=u+63 ("no pending unit of mine < p[k]") on its own
// line; chunk t ready <=> min_k p[k] >= (t+1)*16 (16 units/chunk: 8 bind +
// 8 reas of rows 64t..64t+63).
//   flags: f0 @0, f1 @4096, f1s @8192, prog @12288 (63 x stride-16)
// ---------------------------------------------------------------------------
__global__ __launch_bounds__(256) void k_mega(
    const u16* __restrict__ emb,
    const u16* __restrict__ Wx0, const u16* __restrict__ Wh0,
    const u16* __restrict__ Wx1, const u16* __restrict__ Wh1,
    const float* __restrict__ bi0, const float* __restrict__ bh0,
    const float* __restrict__ bi1, const float* __restrict__ bh1,
    u16* __restrict__ h0seq,        // [512][64][64][8] block-major
    u16* __restrict__ h1seq,        // [512][64][64][8] block-major
    u16* __restrict__ acat,         // [32768][544]; cols 0..511 h1, 512.. scan out
    int* __restrict__ flags,
    float* __restrict__ r1, float* __restrict__ r2,
    float* __restrict__ fi, float* __restrict__ uu1, float* __restrict__ uu2,
    const float* __restrict__ Wg, const float* __restrict__ bg,
    const u16* __restrict__ dec,
    const u16* __restrict__ initb, const u16* __restrict__ initr,
    const float* __restrict__ Wq, const float* __restrict__ bq,
    const float* __restrict__ Wk, const float* __restrict__ bk,
    const float* __restrict__ Wv, const float* __restrict__ bv,
    const float* __restrict__ lng, const float* __restrict__ lnb,
    const float* __restrict__ Wm1, const float* __restrict__ bm1,
    const float* __restrict__ Wm2, const float* __restrict__ bm2,
    const float* __restrict__ Wsp, const float* __restrict__ bsp)
{
    __shared__ SmemU sm;
    const int tid = threadIdx.x;
    const int blk = blockIdx.x;
    int* f0   = flags;
    int* f1   = flags + 4096;
    int* f1s  = flags + 8192;
    int* prog = flags + 12288;

    if (blk < 128) {
        // =================== wave-autonomous LSTM (R10 verbatim) ==========
        auto& Wx = sm.l.Wx;
        auto& Wh = sm.l.Wh;
        auto& zs = sm.l.zs;
        const int layer = blk >> 6;
        const int me = blk & 63;
        const int jbase = me * 8;
        const int Kx = layer ? 512 : 256;
        const u16* Wxp = layer ? Wx1 : Wx0;
        const u16* Whp = layer ? Wh1 : Wh0;
        const float* bi = layer ? bi1 : bi0;
        const float* bh = layer ? bh1 : bh0;
#pragma unroll
        for (int i = 0; i < 8; i++) {
            int c = tid + i * 256;
            int row = c >> 6, cc = (c & 63) * 8;
            int grow = (row >> 3) * 512 + jbase + (row & 7);
            *(uint4*)(&Wh[row][cc]) = *(const uint4*)(Whp + (size_t)grow * 512 + cc);
        }
        {
            int cpr = Kx >> 3;
            int iters = (32 * cpr) >> 8;
            for (int i = 0; i < iters; i++) {
                int c = tid + i * 256;
                int row = c / cpr, cc = (c % cpr) * 8;
                int grow = (row >> 3) * 512 + jbase + (row & 7);
                *(uint4*)(&Wx[row][cc]) = *(const uint4*)(Wxp + (size_t)grow * Kx + cc);
            }
        }
        const int wave = tid >> 6, lane = tid & 63;
        const int quad = lane >> 4, l16 = lane & 15;
        const int m = wave * 16 + l16;       // global batch row for MFMA A-load
        const int bl = lane >> 2;            // local batch (0..15)
        const int b = wave * 16 + bl;        // global batch for elementwise
        const int jj = (lane & 3) * 2;       // local col pair
        const int hoff = quad * 512 + m * 8; // block-major read offset (elements)
        float bia0[4], bia1[4];
#pragma unroll
        for (int g = 0; g < 4; g++) {
            bia0[g] = bi[g * 512 + jbase + jj]     + bh[g * 512 + jbase + jj];
            bia1[g] = bi[g * 512 + jbase + jj + 1] + bh[g * 512 + jbase + jj + 1];
        }
        const int pollOwn = (wave * 64 + lane) * 16;   // lane polls block `lane`, group `wave`
        const int pubIdx  = (wave * 64 + me) * 16;
        float c0 = 0.f, c1 = 0.f;
        __syncthreads();   // Wx/Wh staged; last barrier before the loop
        for (int t = 0; t < 512; t++) {
            f32x4 acc0 = {}, acc1 = {};
            if (!layer) {
                // x-part (emb, independent of flags)
                const u16* xrow = emb + ((size_t)t * 64 + m) * 256;
#pragma unroll
                for (int kc = 0; kc < 8; kc++) {
                    bf16x8 a  = *(const bf16x8*)(xrow + kc * 32 + quad * 8);
                    bf16x8 w0 = *(const bf16x8*)(&Wx[l16][kc * 32 + quad * 8]);
                    bf16x8 w1 = *(const bf16x8*)(&Wx[16 + l16][kc * 32 + quad * 8]);
                    acc0 = __builtin_amdgcn_mfma_f32_16x16x32_bf16(a, w0, acc0, 0, 0, 0);
                    acc1 = __builtin_amdgcn_mfma_f32_16x16x32_bf16(a, w1, acc1, 0, 0, 0);
                }
                if (t > 0) {   // wait for group-w h0[t-1]
                    int it = 0;
                    for (;;) {
                        int a = ag_load(f0 + pollOwn);
                        if (__all(a >= t)) break;
                        if (++it > 3000000) break;
                        __builtin_amdgcn_s_sleep(1);
                    }
                    const u16* hrd = h0seq + (size_t)(t - 1) * 32768 + hoff;
#pragma unroll
                    for (int kc = 0; kc < 16; kc++) {
                        bf16x8 a  = *(const bf16x8*)(hrd + kc * 2048);
                        bf16x8 w0 = *(const bf16x8*)(&Wh[l16][kc * 32 + quad * 8]);
                        bf16x8 w1 = *(const bf16x8*)(&Wh[16 + l16][kc * 32 + quad * 8]);
                        acc0 = __builtin_amdgcn_mfma_f32_16x16x32_bf16(a, w0, acc0, 0, 0, 0);
                        acc1 = __builtin_amdgcn_mfma_f32_16x16x32_bf16(a, w1, acc1, 0, 0, 0);
                    }
                }
            } else {
                // wait for h0[t] (f0 group w >= t+1), then x-part
                {
                    int it = 0;
                    for (;;) {
                        int a = ag_load(f0 + pollOwn);
                        if (__all(a >= t + 1)) break;
                        if (++it > 3000000) break;
                        __builtin_amdgcn_s_sleep(1);
                    }
                }
                const u16* xrow = h0seq + (size_t)t * 32768 + hoff;
#pragma unroll
                for (int kc = 0; kc < 16; kc++) {
                    bf16x8 a  = *(const bf16x8*)(xrow + kc * 2048);
                    bf16x8 w0 = *(const bf16x8*)(&Wx[l16][kc * 32 + quad * 8]);
                    bf16x8 w1 = *(const bf16x8*)(&Wx[16 + l16][kc * 32 + quad * 8]);
                    acc0 = __builtin_amdgcn_mfma_f32_16x16x32_bf16(a, w0, acc0, 0, 0, 0);
                    acc1 = __builtin_amdgcn_mfma_f32_16x16x32_bf16(a, w1, acc1, 0, 0, 0);
                }
                if (t > 0) {   // wait for group-w h1[t-1], then h-part
                    int it = 0;
                    for (;;) {
                        int a = ag_load(f1 + pollOwn);
                        if (__all(a >= t)) break;
                        if (++it > 3000000) break;
                        __builtin_amdgcn_s_sleep(1);
                    }
                    const u16* hrd = h1seq + (size_t)(t - 1) * 32768 + hoff;
#pragma unroll
                    for (int kc = 0; kc < 16; kc++) {
                        bf16x8 a  = *(const bf16x8*)(hrd + kc * 2048);
                        bf16x8 w0 = *(const bf16x8*)(&Wh[l16][kc * 32 + quad * 8]);
                        bf16x8 w1 = *(const bf16x8*)(&Wh[16 + l16][kc * 32 + quad * 8]);
                        acc0 = __builtin_amdgcn_mfma_f32_16x16x32_bf16(a, w0, acc0, 0, 0, 0);
                        acc1 = __builtin_amdgcn_mfma_f32_16x16x32_bf16(a, w1, acc1, 0, 0, 0);
                    }
                }
            }
            // wave-local z staging (no barrier: same-wave LDS, lgkmcnt only)
#pragma unroll
            for (int r = 0; r < 4; r++) {
                zs[wave][quad * 4 + r][l16]      = acc0[r];
                zs[wave][quad * 4 + r][16 + l16] = acc1[r];
            }
            u16 hb0, hb1;
            {
                float zi0 = zs[wave][bl][jj]      + bia0[0];
                float zf0 = zs[wave][bl][8 + jj]  + bia0[1];
                float zg0 = zs[wave][bl][16 + jj] + bia0[2];
                float zo0 = zs[wave][bl][24 + jj] + bia0[3];
                c0 = sigm(zf0) * c0 + sigm(zi0) * tanhf(zg0);
                float h0v = sigm(zo0) * tanhf(c0);
                float zi1 = zs[wave][bl][jj + 1]      + bia1[0];
                float zf1 = zs[wave][bl][8 + jj + 1]  + bia1[1];
                float zg1 = zs[wave][bl][16 + jj + 1] + bia1[2];
                float zo1 = zs[wave][bl][24 + jj + 1] + bia1[3];
                c1 = sigm(zf1) * c1 + sigm(zi1) * tanhf(zg1);
                float h1v = sigm(zo1) * tanhf(c1);
                hb0 = f2bf(h0v); hb1 = f2bf(h1v);
            }
            if (!layer) {
                // block-major contiguous store: wave writes 256 B (4 full lines)
                llc_store2(h0seq + (size_t)t * 32768 + me * 512 + b * 8 + jj, hb0, hb1);
                __builtin_amdgcn_s_waitcnt(0);
                if (lane == 0) ag_store(f0 + pubIdx, t + 1);
            } else {
                llc_store2(h1seq + (size_t)t * 32768 + me * 512 + b * 8 + jj, hb0, hb1);
                __builtin_amdgcn_s_waitcnt(0);   // drain recurrence copy only
                if (lane == 0) ag_store(f1 + pubIdx, t + 1);
                // row-major copy for scan gate + final GEMM (off critical path)
                llc_store2(acat + ((size_t)t * 64 + b) * 544 + jbase + jj, hb0, hb1);
                __builtin_amdgcn_s_waitcnt(0);
                if (lane == 0) ag_store(f1s + pubIdx, t + 1);
            }
        }
    } else if (blk < 192) {
        // =================== trailing scan + inline gate ==================
        const int sb = blk - 128;          // batch
        const int grp = sb >> 4;           // its batch group
        const int f = tid & 31, rg = tid >> 5;
        float m[4][32];
#pragma unroll
        for (int x = 0; x < 4; x++)
            for (int y = 0; y < 32; y++) m[x][y] = 0.f;
        auto& r1s = sm.c.r1s;
        auto& r2s = sm.c.r2s;
        auto& fis = sm.c.fis;
        auto& u1s = sm.c.u1s;
        auto& u2s = sm.c.u2s;
        auto& red = sm.c.red;
        auto& wred = sm.c.wred;
        auto& gpart = sm.c.gpart;
        float wg0 = Wg[2 * tid], wg1 = Wg[2 * tid + 1];
        float bgv = bg[0];
        for (int t = 0; t < 512; t++) {
            // dual gate: wave0 polls LSTM f1s; wave1 polls slot worker progress
            if (tid < 64) {
                int* p1 = f1s + (grp * 64 + tid) * 16;
                int it = 0;
                for (;;) {
                    int a = ag_load(p1);
                    if (__all(a >= t + 1)) break;
                    if (++it > 3000000) break;
                    __builtin_amdgcn_s_sleep(1);
                }
            } else if (tid < 128) {
                const int k = tid - 64;
                const int* pp = prog + k * 16;
                const int need = (t + 1) * 16;
                int it = 0;
                for (;;) {
                    int a = 0x7FFFFFFF;
                    if (k < 63) a = ag_load(pp);
                    if (__all(a >= need)) break;
                    if (++it > 3000000) break;
                    __builtin_amdgcn_s_sleep(1);
                }
            }
            __syncthreads();
            // preloads AFTER the gates (slot outputs are produced concurrently)
            float pre = 0.f;
            {
                size_t base = ((size_t)t * 64 + sb) * 32;
                if (tid < 32) pre = r1[base + tid];
                else if (tid < 64) pre = r2[base + tid - 32];
                else if (tid < 96) pre = fi[base + tid - 64];
                else if (tid < 128) pre = uu1[base + tid - 96];
                else if (tid < 160) pre = uu2[base + tid - 128];
            }
            {
                const u16* hr = acat + ((size_t)t * 64 + sb) * 544;
                u32 hv = *(const u32*)(hr + 2 * tid);
                float gp = bf2f((u16)hv) * wg0 + bf2f((u16)(hv >> 16)) * wg1;
                for (int mk = 1; mk < 64; mk <<= 1) gp += __shfl_xor(gp, mk, 64);
                if ((tid & 63) == 0) gpart[tid >> 6] = gp;
            }
            if (tid < 32) r1s[tid] = pre;
            else if (tid < 64) r2s[tid - 32] = pre;
            else if (tid < 96) fis[tid - 64] = pre;
            else if (tid < 128) u1s[tid - 96] = pre;
            else if (tid < 160) u2s[tid - 128] = pre;
            __syncthreads();
            float gsh = sigm(gpart[0] + gpart[1] + gpart[2] + gpart[3] + bgv + 1.0f);
            float p = 0.f;
#pragma unroll
            for (int rl = 0; rl < 4; rl++) {
                float s = 0.f;
                for (int ti = 0; ti < 32; ti++) s += r2s[ti] * m[rl][ti];
                p += r1s[rg * 4 + rl] * s;
            }
            red[rg][f] = p;
            __syncthreads();
            float prev = 0.f;
#pragma unroll
            for (int g = 0; g < 8; g++) prev += red[g][f];
            float curo = gsh * (fis[f] - prev) * (1.0f / 32.0f);
            float nsq = 0.f;
#pragma unroll
            for (int rl = 0; rl < 4; rl++) {
                float a = r1s[rg * 4 + rl] * curo;
                for (int ti = 0; ti < 32; ti++) {
                    m[rl][ti] += a * r2s[ti];
                    nsq += m[rl][ti] * m[rl][ti];
                }
            }
            for (int mk = 1; mk < 64; mk <<= 1) nsq += __shfl_xor(nsq, mk, 64);
            __syncthreads();
            if ((tid & 63) == 0) wred[tid >> 6] = nsq;
            __syncthreads();
            float nrm = sqrtf(wred[0] + wred[1] + wred[2] + wred[3]);
            float sc = nrm > 1.0f ? 1.0f / nrm : 1.0f;   // relu(nrm-1)+1 == max(nrm,1)
            float rp = 0.f;
#pragma unroll
            for (int rl = 0; rl < 4; rl++) {
                float s = 0.f;
                for (int ti = 0; ti < 32; ti++) {
                    m[rl][ti] *= sc;
                    s += m[rl][ti] * u2s[ti];
                }
                rp += u1s[rg * 4 + rl] * s;
            }
            red[rg][f] = rp;
            __syncthreads();
            float rv = 0.f;
#pragma unroll
            for (int g = 0; g < 8; g++) rv += red[g][f];
            float mean = rv;
            for (int mk = 1; mk < 32; mk <<= 1) mean += __shfl_xor(mean, mk, 32);
            mean *= (1.0f / 32.0f);
            float d = rv - mean;
            float var = d * d;
            for (int mk = 1; mk < 32; mk <<= 1) var += __shfl_xor(var, mk, 32);
            var *= (1.0f / 32.0f);
            if (tid < 32) {
                float y = d * rsqrtf(var + 1e-5f);
                llc_store_u16(acat + ((size_t)t * 64 + sb) * 544 + 512 + f, f2bf(y));
            }
            __syncthreads();
        }
    } else {
        // =================== persistent slot workers (blk 192..254) =======
        const int wid = blk - 192;   // 0..62
        stage_slot_weights(sm.s, tid, Wq, bq, Wk, bk, Wv, bv, lng, lnb,
                           Wm1, bm1, Wm2, bm2, Wsp, bsp);
        __syncthreads();
        int* myprog = prog + wid * 16;
        for (int u = wid; u < 8192; u += 63) {
            const int t = u >> 4, s = u & 15;
            if (s < 8)
                slot_unit<3>(sm.s, tid, (size_t)t * 64 + s * 8, dec, initb, r1, r2, fi);
            else
                slot_unit<2>(sm.s, tid, (size_t)t * 64 + (s - 8) * 8, dec, initr, uu1, uu2, nullptr);
            __builtin_amdgcn_s_waitcnt(0);   // this thread's output stores acked
            __syncthreads();                 // all threads drained; LDS reusable
            if (tid == 0) ag_store(myprog, u + 63);   // no pending unit < u+63
        }
    }
}

// ---------------------------------------------------------------------------
extern "C" void kernel_launch(void* const* d_in, const int* in_sizes, int n_in,
                              void* d_out, int out_size, void* d_ws, size_t ws_size,
                              hipStream_t stream)
{
    (void)in_sizes; (void)n_in; (void)out_size; (void)ws_size;
    const int*   tokens = (const int*)d_in[0];
    const float* embW  = (const float*)d_in[1];
    const float* Wih0  = (const float*)d_in[2];
    const float* Whh0  = (const float*)d_in[3];
    const float* bih0  = (const float*)d_in[4];
    const float* bhh0  = (const float*)d_in[5];
    const float* Wih1  = (const float*)d_in[6];
    const float* Whh1  = (const float*)d_in[7];
    const float* bih1  = (const float*)d_in[8];
    const float* bhh1  = (const float*)d_in[9];
    const float* Wpi   = (const float*)d_in[10];
    const float* bpi   = (const float*)d_in[11];
    const float* Wq    = (const float*)d_in[12];
    const float* bq    = (const float*)d_in[13];
    const float* Wk    = (const float*)d_in[14];
    const float* bk    = (const float*)d_in[15];
    const float* Wv    = (const float*)d_in[16];
    const float* bv    = (const float*)d_in[17];
    const float* lng   = (const float*)d_in[18];
    const float* lnb   = (const float*)d_in[19];
    const float* Wm1   = (const float*)d_in[20];
    const float* bm1   = (const float*)d_in[21];
    const float* Wm2   = (const float*)d_in[22];
    const float* bm2   = (const float*)d_in[23];
    const float* Wbind = (const float*)d_in[24];
    const float* bbind = (const float*)d_in[25];
    const float* Wreas = (const float*)d_in[26];
    const float* breas = (const float*)d_in[27];
    const float* Wsp   = (const float*)d_in[28];
    const float* bsp   = (const float*)d_in[29];
    const float* Wg    = (const float*)d_in[30];
    const float* bg    = (const float*)d_in[31];
    const float* Wout  = (const float*)d_in[32];
    const float* bout  = (const float*)d_in[33];

    char* ws = (char*)d_ws;
    size_t off = 0;
    auto alloc = [&](size_t bytes) { size_t o = off; off += (bytes + 255) & ~(size_t)255; return o; };
    int*  flags  = (int*)(ws + alloc(16384 * 4));   // f0, f1, f1s, prog
    u16*  emb    = (u16*)(ws + alloc(32768ull * 256 * 2));
    u16*  dec    = (u16*)(ws + alloc(32768ull * 192 * 2));
    u16*  initb  = (u16*)(ws + alloc(32768ull * 96 * 2));
    u16*  initr  = (u16*)(ws + alloc(32768ull * 64 * 2));
    u16*  acat   = (u16*)(ws + alloc(32768ull * 544 * 2));
    u16*  h0seq  = (u16*)(ws + alloc(512ull * 64 * 512 * 2));
    u16*  h1seq  = (u16*)(ws + alloc(512ull * 64 * 512 * 2));
    float* role1 = (float*)(ws + alloc(32768ull * 32 * 4));
    float* role2 = (float*)(ws + alloc(32768ull * 32 * 4));
    float* fill  = (float*)(ws + alloc(32768ull * 32 * 4));
    float* u1v   = (float*)(ws + alloc(32768ull * 32 * 4));
    float* u2v   = (float*)(ws + alloc(32768ull * 32 * 4));
    u16* Wx0b  = (u16*)(ws + alloc(2048ull * 256 * 2));
    u16* Wh0b  = (u16*)(ws + alloc(2048ull * 512 * 2));
    u16* Wx1b  = (u16*)(ws + alloc(2048ull * 512 * 2));
    u16* Wh1b  = (u16*)(ws + alloc(2048ull * 512 * 2));
    u16* Wpib  = (u16*)(ws + alloc(192ull * 256 * 2));
    u16* Wbindb = (u16*)(ws + alloc(96ull * 192 * 2));
    u16* Wreasb = (u16*)(ws + alloc(64ull * 192 * 2));
    u16* Woutb  = (u16*)(ws + alloc(128ull * 544 * 2));

    hipMemsetAsync(flags, 0, 16384 * 4, stream);
    {
        Cvt8 c;
        const float* s[8] = {Wih0, Whh0, Wih1, Whh1, Wpi, Wbind, Wreas, Wout};
        u16* d[8] = {Wx0b, Wh0b, Wx1b, Wh1b, Wpib, Wbindb, Wreasb, Woutb};
        int n[8] = {2048 * 256, 2048 * 512, 2048 * 512, 2048 * 512,
                    192 * 256, 96 * 192, 64 * 192, 128 * 544};
        int acc = 0;
        for (int k = 0; k < 8; k++) { c.s[k] = s[k]; c.d[k] = d[k]; c.off4[k] = acc; acc += n[k] / 4; }
        c.off4[8] = acc;
        k_f2b8<<<(acc + 255) / 256, 256, 0, stream>>>(c);
    }
    k_embed<<<4096, 256, 0, stream>>>(tokens, embW, emb);
    k_gemm_bt<<<dim3(256, 2), 256, 0, stream>>>(emb, 256, Wpib, dec, nullptr, 192, bpi, nullptr, 192, 256);
    k_gemm_bt<<<dim3(256, 1), 256, 0, stream>>>(dec, 192, Wbindb, initb, nullptr, 96, bbind, nullptr, 96, 192);
    k_gemm_bt<<<dim3(256, 1), 256, 0, stream>>>(dec, 192, Wreasb, initr, nullptr, 64, breas, nullptr, 64, 192);
    // fused: LSTM(2 layers) + scan/gate + BOTH slot passes (CU-partitioned)
    k_mega<<<255, 256, 0, stream>>>(emb, Wx0b, Wh0b, Wx1b, Wh1b,
                                    bih0, bhh0, bih1, bhh1,
                                    h0seq, h1seq, acat, flags,
                                    role1, role2, fill, u1v, u2v, Wg, bg,
                                    dec, initb, initr,
                                    Wq, bq, Wk, bk, Wv, bv, lng, lnb,
                                    Wm1, bm1, Wm2, bm2, Wsp, bsp);
    // out = acat @ Wout^T + bout  (fp32 output)
    k_gemm_bt<<<dim3(256, 1), 256, 0, stream>>>(acat, 544, Woutb, nullptr, (float*)d_out, 128, bout, nullptr, 128, 544);
}